// Round 1
// baseline (3009.738 us; speedup 1.0000x reference)
//
#include <hip/hip_runtime.h>
#include <cfloat>

#define THREADS 256

__device__ __forceinline__ float lrelu01(float v){ return v > 0.f ? v : 0.01f * v; }
__device__ __forceinline__ float reluf(float v){ return v > 0.f ? v : 0.f; }
__device__ __forceinline__ float sigmf(float v){ return 1.f / (1.f + __expf(-v)); }
__device__ __forceinline__ float tanhfast(float v){
    float t = __expf(-2.f * fabsf(v));
    float r = (1.f - t) / (1.f + t);
    return v < 0.f ? -r : r;
}
__device__ __forceinline__ float eluf(float v){ return v > 0.f ? v : __expf(v) - 1.f; }
__device__ __forceinline__ float wmaxf(float v){
    #pragma unroll
    for (int o = 32; o > 0; o >>= 1) v = fmaxf(v, __shfl_xor(v, o, 64));
    return v;
}
__device__ __forceinline__ float wsumf(float v){
    #pragma unroll
    for (int o = 32; o > 0; o >>= 1) v += __shfl_xor(v, o, 64);
    return v;
}

// ---------------- CSR build ----------------
__global__ void k_hist(const int* __restrict__ dst, int* __restrict__ cnt, int E){
    int e = blockIdx.x * blockDim.x + threadIdx.x;
    if (e < E) atomicAdd(&cnt[dst[e]], 1);
}

// single-block exclusive scan of cnt[0..N) -> rowptr[0..N]
__global__ void k_scan(const int* __restrict__ cnt, int* __restrict__ rowptr, int N){
    __shared__ int sums[1024];
    int t = threadIdx.x;
    int CH = (N + 1023) / 1024;
    int s0 = t * CH;
    int s1 = min(N, s0 + CH);
    int tot = 0;
    for (int i = s0; i < s1; ++i) tot += cnt[i];
    sums[t] = tot;
    __syncthreads();
    for (int off = 1; off < 1024; off <<= 1){
        int v = (t >= off) ? sums[t - off] : 0;
        __syncthreads();
        sums[t] += v;
        __syncthreads();
    }
    int run = (t == 0) ? 0 : sums[t - 1];
    for (int i = s0; i < s1; ++i){ rowptr[i] = run; run += cnt[i]; }
    if (t == 1023) rowptr[N] = run;
}

__global__ void k_scatter(const int* __restrict__ dst, const int* __restrict__ rowptr,
                          int* __restrict__ cnt2, int* __restrict__ eid, int E){
    int e = blockIdx.x * blockDim.x + threadIdx.x;
    if (e < E){
        int d = dst[e];
        int p = rowptr[d] + atomicAdd(&cnt2[d], 1);
        eid[p] = e;
    }
}

// rowptr for sorted batch array -> rpB[0..B]
__global__ void k_browptr(const int* __restrict__ batch, int* __restrict__ rp, int N, int B){
    int n = blockIdx.x * blockDim.x + threadIdx.x;
    if (n >= N) return;
    int b = batch[n];
    int bp = (n == 0) ? -1 : batch[n - 1];
    for (int g = bp + 1; g <= b; ++g) rp[g] = n;
    if (n == N - 1){ for (int g = b + 1; g <= B; ++g) rp[g] = N; }
}

// ---------------- generic 64-col GEMM: out[n][lane] = act(dot(in[n], W[lane]) + bias) ----------------
// ACT: 0 none, 1 leaky_relu(0.01), 2 relu
template<int ACT>
__global__ void k_gemm64(const float* __restrict__ in, const float* __restrict__ W, int ldw,
                         const float* __restrict__ bias, float* __restrict__ out, int rows){
    const int lane = threadIdx.x & 63;
    const int wid  = blockIdx.x * (blockDim.x >> 6) + (threadIdx.x >> 6);
    const int nw   = gridDim.x * (blockDim.x >> 6);
    float w[64];
    #pragma unroll
    for (int k = 0; k < 64; k += 4){
        float4 t = *(const float4*)(W + (size_t)lane * ldw + k);
        w[k] = t.x; w[k+1] = t.y; w[k+2] = t.z; w[k+3] = t.w;
    }
    const float bb = bias ? bias[lane] : 0.f;
    for (int n = wid; n < rows; n += nw){
        const float* __restrict__ xr = in + (size_t)n * 64;
        float a0 = bb, a1 = 0.f;
        #pragma unroll
        for (int k = 0; k < 64; k += 4){
            float4 t = *(const float4*)(xr + k);
            a0 = fmaf(t.x, w[k],   a0);
            a1 = fmaf(t.y, w[k+1], a1);
            a0 = fmaf(t.z, w[k+2], a0);
            a1 = fmaf(t.w, w[k+3], a1);
        }
        float v = a0 + a1;
        if (ACT == 1) v = lrelu01(v);
        else if (ACT == 2) v = reluf(v);
        out[(size_t)n * 64 + lane] = v;
    }
}

// GRU r/z gates: out = sigmoid(xin@WxC.T + bxC + xp@WhC.T + bhC), C = blockIdx.y (0->R,1->Z)
__global__ void k_gru_rz(const float* __restrict__ xin, const float* __restrict__ xp,
                         const float* __restrict__ wx, const float* __restrict__ wh,
                         const float* __restrict__ bx, const float* __restrict__ bh,
                         float* __restrict__ R, float* __restrict__ Z, int rows){
    const int c = blockIdx.y;
    const int lane = threadIdx.x & 63;
    const int wid  = blockIdx.x * (blockDim.x >> 6) + (threadIdx.x >> 6);
    const int nw   = gridDim.x * (blockDim.x >> 6);
    const float* w1p = wx + (size_t)(c * 64 + lane) * 64;
    const float* w2p = wh + (size_t)(c * 64 + lane) * 64;
    float w1[64], w2[64];
    #pragma unroll
    for (int k = 0; k < 64; k += 4){
        float4 a = *(const float4*)(w1p + k);
        w1[k] = a.x; w1[k+1] = a.y; w1[k+2] = a.z; w1[k+3] = a.w;
        float4 b = *(const float4*)(w2p + k);
        w2[k] = b.x; w2[k+1] = b.y; w2[k+2] = b.z; w2[k+3] = b.w;
    }
    const float bb = bx[c * 64 + lane] + bh[c * 64 + lane];
    float* out = c ? Z : R;
    for (int n = wid; n < rows; n += nw){
        const float* a = xin + (size_t)n * 64;
        const float* h = xp  + (size_t)n * 64;
        float acc = bb, acc1 = 0.f;
        #pragma unroll
        for (int k = 0; k < 64; k += 4){
            float4 t = *(const float4*)(a + k);
            acc  = fmaf(t.x, w1[k],   acc);
            acc1 = fmaf(t.y, w1[k+1], acc1);
            acc  = fmaf(t.z, w1[k+2], acc);
            acc1 = fmaf(t.w, w1[k+3], acc1);
        }
        #pragma unroll
        for (int k = 0; k < 64; k += 4){
            float4 t = *(const float4*)(h + k);
            acc  = fmaf(t.x, w2[k],   acc);
            acc1 = fmaf(t.y, w2[k+1], acc1);
            acc  = fmaf(t.z, w2[k+2], acc);
            acc1 = fmaf(t.w, w2[k+3], acc1);
        }
        out[(size_t)n * 64 + lane] = sigmf(acc + acc1);
    }
}

// GRU finish: hn = xp@WhN.T + bhN; n = tanh(xn + r*hn); out = relu((1-z)*n + z*xp)
// out may alias R (elementwise-safe), must NOT alias xp.
__global__ void k_gru_fin(const float* __restrict__ xp, const float* __restrict__ whn,
                          const float* __restrict__ bhn,
                          const float* __restrict__ R, const float* __restrict__ Z,
                          const float* __restrict__ XN, float* __restrict__ out, int rows){
    const int lane = threadIdx.x & 63;
    const int wid  = blockIdx.x * (blockDim.x >> 6) + (threadIdx.x >> 6);
    const int nw   = gridDim.x * (blockDim.x >> 6);
    float w[64];
    #pragma unroll
    for (int k = 0; k < 64; k += 4){
        float4 t = *(const float4*)(whn + (size_t)lane * 64 + k);
        w[k] = t.x; w[k+1] = t.y; w[k+2] = t.z; w[k+3] = t.w;
    }
    const float bb = bhn[lane];
    for (int n = wid; n < rows; n += nw){
        const float* h = xp + (size_t)n * 64;
        float a0 = bb, a1 = 0.f;
        #pragma unroll
        for (int k = 0; k < 64; k += 4){
            float4 t = *(const float4*)(h + k);
            a0 = fmaf(t.x, w[k],   a0);
            a1 = fmaf(t.y, w[k+1], a1);
            a0 = fmaf(t.z, w[k+2], a0);
            a1 = fmaf(t.w, w[k+3], a1);
        }
        float hn = a0 + a1;
        size_t idx = (size_t)n * 64 + lane;
        float r = R[idx], z = Z[idx], xn = XN[idx], hp = h[lane];
        float nn = tanhfast(fmaf(r, hn, xn));
        out[idx] = reluf((1.f - z) * nn + z * hp);
    }
}

// per-row dot with a 64-vector (two variants batched over gridDim.y)
__global__ void k_rowdot2(const float* __restrict__ in, const float* __restrict__ v0,
                          const float* __restrict__ v1, float* __restrict__ o0,
                          float* __restrict__ o1, int rows){
    const float* vec = blockIdx.y ? v1 : v0;
    float* out = blockIdx.y ? o1 : o0;
    const int lane = threadIdx.x & 63;
    const int wid  = blockIdx.x * (blockDim.x >> 6) + (threadIdx.x >> 6);
    const int nw   = gridDim.x * (blockDim.x >> 6);
    const float vl = vec[lane];
    for (int n = wid; n < rows; n += nw){
        float p = in[(size_t)n * 64 + lane] * vl;
        float s = wsumf(p);
        if (lane == 0) out[n] = s;
    }
}

// GATEConv per-edge logit
__global__ void k_gate_logit(const float* __restrict__ np1, const float* __restrict__ ea,
                             const float* __restrict__ w1,  // gate_lin1_w [64][80]
                             const float* __restrict__ attl, const float* __restrict__ nat,
                             const int* __restrict__ src, const int* __restrict__ dstv,
                             float* __restrict__ logit, int E){
    __shared__ float wlds[16 * 64];  // [j][k] = w1[k*80 + 64 + j]
    __shared__ float al[64];
    for (int i = threadIdx.x; i < 1024; i += blockDim.x){
        int j = i >> 6, k = i & 63;
        wlds[i] = w1[k * 80 + 64 + j];
    }
    if (threadIdx.x < 64) al[threadIdx.x] = attl[threadIdx.x];
    __syncthreads();
    int e = blockIdx.x * blockDim.x + threadIdx.x;
    if (e >= E) return;
    int s = src[e], d = dstv[e];
    float acc[64];
    const float* nr = np1 + (size_t)s * 64;
    #pragma unroll
    for (int k = 0; k < 64; k += 4){
        float4 t = *(const float4*)(nr + k);
        acc[k] = t.x; acc[k+1] = t.y; acc[k+2] = t.z; acc[k+3] = t.w;
    }
    const float* er = ea + (size_t)e * 16;
    #pragma unroll
    for (int j = 0; j < 16; ++j){
        float v = er[j];
        #pragma unroll
        for (int k = 0; k < 64; k += 4){
            float4 t = *(const float4*)&wlds[j * 64 + k];
            acc[k]   = fmaf(v, t.x, acc[k]);
            acc[k+1] = fmaf(v, t.y, acc[k+1]);
            acc[k+2] = fmaf(v, t.z, acc[k+2]);
            acc[k+3] = fmaf(v, t.w, acc[k+3]);
        }
    }
    float l = 0.f;
    #pragma unroll
    for (int k = 0; k < 64; ++k) l = fmaf(lrelu01(acc[k]), al[k], l);
    logit[e] = lrelu01(l + nat[d]);
}

// GATE aggregate: softmax over stored logits (CSR), h = sum alpha*xg[src] + bias, write elu(h)
__global__ void k_gate_agg(const float* __restrict__ logit, const int* __restrict__ eid,
                           const int* __restrict__ rowptr, const int* __restrict__ src,
                           const float* __restrict__ xg, const float* __restrict__ bias,
                           float* __restrict__ xin, int N){
    const int lane = threadIdx.x & 63;
    const int d = blockIdx.x * (blockDim.x >> 6) + (threadIdx.x >> 6);
    if (d >= N) return;
    int r0 = rowptr[d], r1 = rowptr[d + 1];
    float m = -3.4e38f;
    for (int j = r0 + lane; j < r1; j += 64) m = fmaxf(m, logit[eid[j]]);
    m = wmaxf(m);
    float s = 0.f, hk = 0.f;
    for (int j = r0; j < r1; ++j){
        int e = eid[j];
        float w = __expf(logit[e] - m);
        s += w;
        hk = fmaf(w, xg[(size_t)src[e] * 64 + lane], hk);
    }
    float h = hk / (s + 1e-16f) + bias[lane];
    xin[(size_t)d * 64 + lane] = eluf(h);
}

// GAT aggregate: logits computed inline from asrc[src]+adst[d]
__global__ void k_atom_agg(const float* __restrict__ asrc, const float* __restrict__ adst,
                           const int* __restrict__ eid, const int* __restrict__ rowptr,
                           const int* __restrict__ src, const float* __restrict__ xl,
                           const float* __restrict__ bias, float* __restrict__ xin, int N){
    const int lane = threadIdx.x & 63;
    const int d = blockIdx.x * (blockDim.x >> 6) + (threadIdx.x >> 6);
    if (d >= N) return;
    int r0 = rowptr[d], r1 = rowptr[d + 1];
    const float ad = adst[d];
    float m = -3.4e38f;
    for (int j = r0 + lane; j < r1; j += 64){
        int e = eid[j];
        m = fmaxf(m, lrelu01(asrc[src[e]] + ad));
    }
    m = wmaxf(m);
    float s = 0.f, hk = 0.f;
    for (int j = r0; j < r1; ++j){
        int e = eid[j];
        int sn = src[e];
        float l = lrelu01(asrc[sn] + ad);
        float w = __expf(l - m);
        s += w;
        hk = fmaf(w, xl[(size_t)sn * 64 + lane], hk);
    }
    float h = hk / (s + 1e-16f) + bias[lane];
    xin[(size_t)d * 64 + lane] = eluf(h);
}

// out0[b] = relu(sum over nodes of graph b)
__global__ void k_out0(const float* __restrict__ x, const int* __restrict__ rpB,
                       float* __restrict__ outB, int B){
    const int lane = threadIdx.x & 63;
    const int b = blockIdx.x * (blockDim.x >> 6) + (threadIdx.x >> 6);
    if (b >= B) return;
    int r0 = rpB[b], r1 = rpB[b + 1];
    float a = 0.f;
    for (int n = r0; n < r1; ++n) a += x[(size_t)n * 64 + lane];
    outB[(size_t)b * 64 + lane] = reluf(a);
}

// readout attention step: g = (out@W.T)@attdst, softmax over graph nodes, hB = elu(agg + bias)
__global__ void k_mol_attn(const float* __restrict__ outB, const float* __restrict__ W,
                           const float* __restrict__ attdst, const float* __restrict__ a_src,
                           const float* __restrict__ xs, const int* __restrict__ rpB,
                           const float* __restrict__ bias, float* __restrict__ hB, int B){
    const int lane = threadIdx.x & 63;
    const int b = blockIdx.x * (blockDim.x >> 6) + (threadIdx.x >> 6);
    if (b >= B) return;
    float w[64];
    #pragma unroll
    for (int k = 0; k < 64; k += 4){
        float4 t = *(const float4*)(W + (size_t)lane * 64 + k);
        w[k] = t.x; w[k+1] = t.y; w[k+2] = t.z; w[k+3] = t.w;
    }
    const float* orow = outB + (size_t)b * 64;
    float acc = 0.f;
    #pragma unroll
    for (int k = 0; k < 64; ++k) acc = fmaf(orow[k], w[k], acc);
    float g = wsumf(acc * attdst[lane]);
    int r0 = rpB[b], r1 = rpB[b + 1];
    float m = -3.4e38f;
    for (int n = r0 + lane; n < r1; n += 64) m = fmaxf(m, lrelu01(a_src[n] + g));
    m = wmaxf(m);
    float s = 0.f, hk = 0.f;
    for (int n = r0; n < r1; ++n){
        float l = lrelu01(a_src[n] + g);
        float ww = __expf(l - m);
        s += ww;
        hk = fmaf(ww, xs[(size_t)n * 64 + lane], hk);
    }
    hB[(size_t)b * 64 + lane] = eluf(hk / (s + 1e-16f) + bias[lane]);
}

// regression head: LayerNorm -> relu(64x64) -> relu(64x64) -> (Px64)
__global__ void k_head(const float* __restrict__ emb, const float* __restrict__ lng,
                       const float* __restrict__ lnb,
                       const float* __restrict__ w1, const float* __restrict__ b1,
                       const float* __restrict__ w2, const float* __restrict__ b2,
                       const float* __restrict__ w3, const float* __restrict__ b3,
                       float* __restrict__ out, int B, int P){
    __shared__ float w1t[4096], w2t[4096];
    __shared__ float buf0[4][64], buf1[4][64];
    for (int i = threadIdx.x; i < 4096; i += blockDim.x){
        int h = i >> 6, k = i & 63;
        w1t[k * 64 + h] = w1[i];
        w2t[k * 64 + h] = w2[i];
    }
    __syncthreads();
    const int lane = threadIdx.x & 63;
    const int wv = threadIdx.x >> 6;
    int b = blockIdx.x * (blockDim.x >> 6) + wv;
    bool act = b < B;
    float v = act ? emb[(size_t)b * 64 + lane] : 0.f;
    float mean = wsumf(v) * 0.015625f;
    float dv = v - mean;
    float var = wsumf(dv * dv) * 0.015625f;
    float y = dv * rsqrtf(var + 1e-5f) * lng[lane] + lnb[lane];
    buf0[wv][lane] = y;
    __syncthreads();
    float a1 = b1[lane];
    #pragma unroll
    for (int k = 0; k < 64; ++k) a1 = fmaf(buf0[wv][k], w1t[k * 64 + lane], a1);
    float y1 = reluf(a1);
    buf1[wv][lane] = y1;
    __syncthreads();
    float a2 = b2[lane];
    #pragma unroll
    for (int k = 0; k < 64; ++k) a2 = fmaf(buf1[wv][k], w2t[k * 64 + lane], a2);
    float y2 = reluf(a2);
    for (int p = 0; p < P; ++p){
        float s = wsumf(y2 * w3[p * 64 + lane]);
        if (lane == 0 && act) out[(size_t)b * P + p] = s + b3[p];
    }
}

extern "C" void kernel_launch(void* const* d_in, const int* in_sizes, int n_in,
                              void* d_out, int out_size, void* d_ws, size_t ws_size,
                              hipStream_t stream){
    const float* x       = (const float*)d_in[0];
    const float* eattr   = (const float*)d_in[1];
    const float* lin1_w  = (const float*)d_in[2];
    const float* lin1_b  = (const float*)d_in[3];
    const float* g_l1w   = (const float*)d_in[4];
    const float* g_l2w   = (const float*)d_in[5];
    const float* g_attl  = (const float*)d_in[6];
    const float* g_attr  = (const float*)d_in[7];
    const float* g_bias  = (const float*)d_in[8];
    const float* gru0_wx = (const float*)d_in[9];
    const float* gru0_wh = (const float*)d_in[10];
    const float* gru0_bx = (const float*)d_in[11];
    const float* gru0_bh = (const float*)d_in[12];
    const float* a_linw  = (const float*)d_in[13];
    const float* a_asrc  = (const float*)d_in[14];
    const float* a_adst  = (const float*)d_in[15];
    const float* a_bias  = (const float*)d_in[16];
    const float* a_gwx   = (const float*)d_in[17];
    const float* a_gwh   = (const float*)d_in[18];
    const float* a_gbx   = (const float*)d_in[19];
    const float* a_gbh   = (const float*)d_in[20];
    const float* m_linw  = (const float*)d_in[21];
    const float* m_asrcv = (const float*)d_in[22];
    const float* m_adstv = (const float*)d_in[23];
    const float* m_bias  = (const float*)d_in[24];
    const float* m_gwx   = (const float*)d_in[25];
    const float* m_gwh   = (const float*)d_in[26];
    const float* m_gbx   = (const float*)d_in[27];
    const float* m_gbh   = (const float*)d_in[28];
    const float* lin2_w  = (const float*)d_in[29];
    const float* lin2_b  = (const float*)d_in[30];
    const float* ln_g    = (const float*)d_in[31];
    const float* ln_b    = (const float*)d_in[32];
    const float* h1_w    = (const float*)d_in[33];
    const float* h1_b    = (const float*)d_in[34];
    const float* h2_w    = (const float*)d_in[35];
    const float* h2_b    = (const float*)d_in[36];
    const float* h3_w    = (const float*)d_in[37];
    const float* h3_b    = (const float*)d_in[38];
    const int*   ei      = (const int*)d_in[39];
    const int*   batch   = (const int*)d_in[40];
    float* out = (float*)d_out;

    const int N = in_sizes[0] / 64;
    const int E = in_sizes[1] / 16;
    const int P = in_sizes[38];
    const int B = out_size / (P > 0 ? P : 1);
    const int* srcv = ei;
    const int* dstv = ei + E;

    // ---- workspace layout ----
    float* Wb = (float*)d_ws;
    size_t nb = (size_t)N * 64;
    size_t bb = (size_t)B * 64;
    float* P0 = Wb;
    float* P1 = P0 + nb;
    float* P2 = P1 + nb;
    float* P3 = P2 + nb;
    float* P4 = P3 + nb;
    float* logitE = P4 + nb;
    float* scal  = logitE + E;       // 2N floats (nat / asrc,adst / a_src)
    float* outB0 = scal + 2 * (size_t)N;
    float* outB1 = outB0 + bb;
    float* hB    = outB1 + bb;
    float* RB    = hB + bb;
    float* ZB    = RB + bb;
    float* XNB   = ZB + bb;
    int* eid    = (int*)(XNB + bb);
    int* rowptr = eid + E;
    int* cnt    = rowptr + (N + 1);
    int* cnt2   = cnt + N;
    int* rpB    = cnt2 + N;
    size_t need = (size_t)((char*)(rpB + B + 1) - (char*)d_ws);
    if (need > ws_size) return;  // insufficient scratch; avoid corruption
    float* embB = RB;            // reuse (RB dead by then)

    dim3 blk(THREADS);
    int gE   = (E + THREADS - 1) / THREADS;
    int gN4  = (N + 3) / 4;
    int gB4  = (B + 3) / 4;
    int gN256 = (N + THREADS - 1) / THREADS;
    int GS_N = 1024;   // grid-stride blocks for N-row GEMMs
    int GS_B = 128;    // for B-row GEMMs

    // ---- CSR build ----
    hipMemsetAsync(cnt, 0, sizeof(int) * 2 * (size_t)N, stream);
    k_hist<<<gE, blk, 0, stream>>>(dstv, cnt, E);
    k_scan<<<1, 1024, 0, stream>>>(cnt, rowptr, N);
    k_scatter<<<gE, blk, 0, stream>>>(dstv, rowptr, cnt2, eid, E);
    k_browptr<<<gN256, blk, 0, stream>>>(batch, rpB, N, B);

    // ---- phase 0: x1 = lrelu(x@lin1_w.T + b) -> P0 ----
    k_gemm64<1><<<GS_N, blk, 0, stream>>>(x, lin1_w, 64, lin1_b, P0, N);

    // ---- GATEConv ----
    k_gemm64<0><<<GS_N, blk, 0, stream>>>(P0, g_l1w, 80, nullptr, P1, N);   // np1
    k_gemm64<0><<<GS_N, blk, 0, stream>>>(P0, g_l2w, 64, nullptr, P2, N);   // xg
    k_rowdot2<<<dim3(gN4, 1), blk, 0, stream>>>(P0, g_attr, g_attr, scal, scal, N);  // nat
    k_gate_logit<<<gE, blk, 0, stream>>>(P1, eattr, g_l1w, g_attl, scal, srcv, dstv, logitE, E);
    k_gate_agg<<<gN4, blk, 0, stream>>>(logitE, eid, rowptr, srcv, P2, g_bias, P3, N);  // xin -> P3
    // GRU0: xin=P3, xprev=P0 -> x=P1
    k_gru_rz<<<dim3(GS_N, 2), blk, 0, stream>>>(P3, P0, gru0_wx, gru0_wh, gru0_bx, gru0_bh, P1, P2, N);
    k_gemm64<0><<<GS_N, blk, 0, stream>>>(P3, gru0_wx + 8192, 64, gru0_bx + 128, P4, N); // XN
    k_gru_fin<<<GS_N, blk, 0, stream>>>(P0, gru0_wh + 8192, gru0_bh + 128, P1, P2, P4, P1, N);

    // ---- atom layer 0: x=P1 -> x=P4 ----
    k_gemm64<0><<<GS_N, blk, 0, stream>>>(P1, a_linw, 64, nullptr, P0, N);  // xl -> P0
    k_rowdot2<<<dim3(gN4, 2), blk, 0, stream>>>(P0, a_asrc, a_adst, scal, scal + N, N);
    k_atom_agg<<<gN4, blk, 0, stream>>>(scal, scal + N, eid, rowptr, srcv, P0, a_bias, P3, N);
    k_gru_rz<<<dim3(GS_N, 2), blk, 0, stream>>>(P3, P1, a_gwx, a_gwh, a_gbx, a_gbh, P4, P2, N);
    k_gemm64<0><<<GS_N, blk, 0, stream>>>(P3, a_gwx + 8192, 64, a_gbx + 128, P0, N);
    k_gru_fin<<<GS_N, blk, 0, stream>>>(P1, a_gwh + 8192, a_gbh + 128, P4, P2, P0, P4, N);

    // ---- atom layer 1: x=P4 -> x=P1 ----
    k_gemm64<0><<<GS_N, blk, 0, stream>>>(P4, a_linw + 4096, 64, nullptr, P0, N);
    k_rowdot2<<<dim3(gN4, 2), blk, 0, stream>>>(P0, a_asrc + 64, a_adst + 64, scal, scal + N, N);
    k_atom_agg<<<gN4, blk, 0, stream>>>(scal, scal + N, eid, rowptr, srcv, P0, a_bias + 64, P3, N);
    k_gru_rz<<<dim3(GS_N, 2), blk, 0, stream>>>(P3, P4, a_gwx + 12288, a_gwh + 12288,
                                                a_gbx + 192, a_gbh + 192, P1, P2, N);
    k_gemm64<0><<<GS_N, blk, 0, stream>>>(P3, a_gwx + 12288 + 8192, 64, a_gbx + 192 + 128, P0, N);
    k_gru_fin<<<GS_N, blk, 0, stream>>>(P4, a_gwh + 12288 + 8192, a_gbh + 192 + 128, P1, P2, P0, P1, N);

    // ---- readout: x=P1 ----
    k_gemm64<0><<<GS_N, blk, 0, stream>>>(P1, m_linw, 64, nullptr, P0, N);          // xs -> P0
    k_rowdot2<<<dim3(gN4, 1), blk, 0, stream>>>(P0, m_asrcv, m_asrcv, scal, scal, N); // a_src
    k_out0<<<gB4, blk, 0, stream>>>(P1, rpB, outB0, B);
    float* cur = outB0;
    float* nxt = outB1;
    for (int t = 0; t < 3; ++t){
        k_mol_attn<<<gB4, blk, 0, stream>>>(cur, m_linw, m_adstv, scal, P0, rpB, m_bias, hB, B);
        k_gru_rz<<<dim3(GS_B, 2), blk, 0, stream>>>(hB, cur, m_gwx, m_gwh, m_gbx, m_gbh, RB, ZB, B);
        k_gemm64<0><<<GS_B, blk, 0, stream>>>(hB, m_gwx + 8192, 64, m_gbx + 128, XNB, B);
        k_gru_fin<<<GS_B, blk, 0, stream>>>(cur, m_gwh + 8192, m_gbh + 128, RB, ZB, XNB, nxt, B);
        float* tmp = cur; cur = nxt; nxt = tmp;
    }

    // ---- head ----
    k_gemm64<0><<<GS_B, blk, 0, stream>>>(cur, lin2_w, 64, lin2_b, embB, B);
    k_head<<<gB4, blk, 0, stream>>>(embB, ln_g, ln_b, h1_w, h1_b, h2_w, h2_b, h3_w, h3_b, out, B, P);
}

// Round 2
// 1904.879 us; speedup vs baseline: 1.5800x; 1.5800x over previous
//
#include <hip/hip_runtime.h>
#include <cfloat>

#define THREADS 256

__device__ __forceinline__ float lrelu01(float v){ return v > 0.f ? v : 0.01f * v; }
__device__ __forceinline__ float reluf(float v){ return v > 0.f ? v : 0.f; }
__device__ __forceinline__ float sigmf(float v){ return 1.f / (1.f + __expf(-v)); }
__device__ __forceinline__ float tanhfast(float v){
    float t = __expf(-2.f * fabsf(v));
    float r = (1.f - t) / (1.f + t);
    return v < 0.f ? -r : r;
}
__device__ __forceinline__ float eluf(float v){ return v > 0.f ? v : __expf(v) - 1.f; }
__device__ __forceinline__ float wmaxf(float v){
    #pragma unroll
    for (int o = 32; o > 0; o >>= 1) v = fmaxf(v, __shfl_xor(v, o, 64));
    return v;
}
__device__ __forceinline__ float wsumf(float v){
    #pragma unroll
    for (int o = 32; o > 0; o >>= 1) v += __shfl_xor(v, o, 64);
    return v;
}

// ---------------- CSR build ----------------
__global__ void k_hist(const int* __restrict__ dst, int* __restrict__ cnt, int E){
    int e = blockIdx.x * blockDim.x + threadIdx.x;
    if (e < E) atomicAdd(&cnt[dst[e]], 1);
}

__global__ void k_scan(const int* __restrict__ cnt, int* __restrict__ rowptr, int N){
    __shared__ int sums[1024];
    int t = threadIdx.x;
    int CH = (N + 1023) / 1024;
    int s0 = t * CH;
    int s1 = min(N, s0 + CH);
    int tot = 0;
    for (int i = s0; i < s1; ++i) tot += cnt[i];
    sums[t] = tot;
    __syncthreads();
    for (int off = 1; off < 1024; off <<= 1){
        int v = (t >= off) ? sums[t - off] : 0;
        __syncthreads();
        sums[t] += v;
        __syncthreads();
    }
    int run = (t == 0) ? 0 : sums[t - 1];
    for (int i = s0; i < s1; ++i){ rowptr[i] = run; run += cnt[i]; }
    if (t == 1023) rowptr[N] = run;
}

__global__ void k_scatter(const int* __restrict__ dst, const int* __restrict__ rowptr,
                          int* __restrict__ cnt2, int* __restrict__ eid, int E){
    int e = blockIdx.x * blockDim.x + threadIdx.x;
    if (e < E){
        int d = dst[e];
        int p = rowptr[d] + atomicAdd(&cnt2[d], 1);
        eid[p] = e;
    }
}

__global__ void k_browptr(const int* __restrict__ batch, int* __restrict__ rp, int N, int B){
    int n = blockIdx.x * blockDim.x + threadIdx.x;
    if (n >= N) return;
    int b = batch[n];
    int bp = (n == 0) ? -1 : batch[n - 1];
    for (int g = bp + 1; g <= b; ++g) rp[g] = n;
    if (n == N - 1){ for (int g = b + 1; g <= B; ++g) rp[g] = N; }
}

// ---------------- 64-col GEMM: out[n][lane] = act(dot(in[n], W[lane]) + bias) ----------------
template<int ACT>
__global__ __launch_bounds__(THREADS, 4)
void k_gemm64(const float* __restrict__ in, const float* __restrict__ W, int ldw,
              const float* __restrict__ bias, float* __restrict__ out, int rows){
    const int lane = threadIdx.x & 63;
    const int wid  = blockIdx.x * (blockDim.x >> 6) + (threadIdx.x >> 6);
    const int nw   = gridDim.x * (blockDim.x >> 6);
    float w[64];
    #pragma unroll
    for (int k = 0; k < 64; k += 4){
        float4 t = *(const float4*)(W + (size_t)lane * ldw + k);
        w[k] = t.x; w[k+1] = t.y; w[k+2] = t.z; w[k+3] = t.w;
    }
    const float bb = bias ? bias[lane] : 0.f;
    for (int n = wid; n < rows; n += nw){
        const float* __restrict__ xr = in + (size_t)n * 64;
        float a0 = bb, a1 = 0.f;
        #pragma unroll
        for (int k = 0; k < 64; k += 4){
            float4 t = *(const float4*)(xr + k);
            a0 = fmaf(t.x, w[k],   a0);
            a1 = fmaf(t.y, w[k+1], a1);
            a0 = fmaf(t.z, w[k+2], a0);
            a1 = fmaf(t.w, w[k+3], a1);
        }
        float v = a0 + a1;
        if (ACT == 1) v = lrelu01(v);
        else if (ACT == 2) v = reluf(v);
        out[(size_t)n * 64 + lane] = v;
    }
}

// GEMM + fused row-dot epilogue: o0[n] = dot(outrow, v0), o1[n] = dot(outrow, v1)
template<int ACT>
__global__ __launch_bounds__(THREADS, 4)
void k_gemm64d(const float* __restrict__ in, const float* __restrict__ W, int ldw,
               const float* __restrict__ bias, float* __restrict__ out,
               const float* __restrict__ v0, const float* __restrict__ v1,
               float* __restrict__ o0, float* __restrict__ o1, int rows){
    const int lane = threadIdx.x & 63;
    const int wid  = blockIdx.x * (blockDim.x >> 6) + (threadIdx.x >> 6);
    const int nw   = gridDim.x * (blockDim.x >> 6);
    float w[64];
    #pragma unroll
    for (int k = 0; k < 64; k += 4){
        float4 t = *(const float4*)(W + (size_t)lane * ldw + k);
        w[k] = t.x; w[k+1] = t.y; w[k+2] = t.z; w[k+3] = t.w;
    }
    const float bb = bias ? bias[lane] : 0.f;
    const float vl0 = v0 ? v0[lane] : 0.f;
    const float vl1 = v1 ? v1[lane] : 0.f;
    for (int n = wid; n < rows; n += nw){
        const float* __restrict__ xr = in + (size_t)n * 64;
        float a0 = bb, a1 = 0.f;
        #pragma unroll
        for (int k = 0; k < 64; k += 4){
            float4 t = *(const float4*)(xr + k);
            a0 = fmaf(t.x, w[k],   a0);
            a1 = fmaf(t.y, w[k+1], a1);
            a0 = fmaf(t.z, w[k+2], a0);
            a1 = fmaf(t.w, w[k+3], a1);
        }
        float v = a0 + a1;
        if (ACT == 1) v = lrelu01(v);
        else if (ACT == 2) v = reluf(v);
        out[(size_t)n * 64 + lane] = v;
        float s0 = wsumf(v * vl0);
        float s1 = wsumf(v * vl1);
        if (lane == 0){
            if (o0) o0[n] = s0;
            if (o1) o1[n] = s1;
        }
    }
}

// GRU r/z gates: out = sigmoid(xin@WxC.T + bxC + xp@WhC.T + bhC), C = blockIdx.y (0->R,1->Z)
__global__ __launch_bounds__(THREADS, 2)
void k_gru_rz(const float* __restrict__ xin, const float* __restrict__ xp,
              const float* __restrict__ wx, const float* __restrict__ wh,
              const float* __restrict__ bx, const float* __restrict__ bh,
              float* __restrict__ R, float* __restrict__ Z, int rows){
    const int c = blockIdx.y;
    const int lane = threadIdx.x & 63;
    const int wid  = blockIdx.x * (blockDim.x >> 6) + (threadIdx.x >> 6);
    const int nw   = gridDim.x * (blockDim.x >> 6);
    const float* w1p = wx + (size_t)(c * 64 + lane) * 64;
    const float* w2p = wh + (size_t)(c * 64 + lane) * 64;
    float w1[64], w2[64];
    #pragma unroll
    for (int k = 0; k < 64; k += 4){
        float4 a = *(const float4*)(w1p + k);
        w1[k] = a.x; w1[k+1] = a.y; w1[k+2] = a.z; w1[k+3] = a.w;
        float4 b = *(const float4*)(w2p + k);
        w2[k] = b.x; w2[k+1] = b.y; w2[k+2] = b.z; w2[k+3] = b.w;
    }
    const float bb = bx[c * 64 + lane] + bh[c * 64 + lane];
    float* out = c ? Z : R;
    for (int n = wid; n < rows; n += nw){
        const float* a = xin + (size_t)n * 64;
        const float* h = xp  + (size_t)n * 64;
        float acc = bb, acc1 = 0.f;
        #pragma unroll
        for (int k = 0; k < 64; k += 4){
            float4 t = *(const float4*)(a + k);
            acc  = fmaf(t.x, w1[k],   acc);
            acc1 = fmaf(t.y, w1[k+1], acc1);
            acc  = fmaf(t.z, w1[k+2], acc);
            acc1 = fmaf(t.w, w1[k+3], acc1);
        }
        #pragma unroll
        for (int k = 0; k < 64; k += 4){
            float4 t = *(const float4*)(h + k);
            acc  = fmaf(t.x, w2[k],   acc);
            acc1 = fmaf(t.y, w2[k+1], acc1);
            acc  = fmaf(t.z, w2[k+2], acc);
            acc1 = fmaf(t.w, w2[k+3], acc1);
        }
        out[(size_t)n * 64 + lane] = sigmf(acc + acc1);
    }
}

// GRU finish (fused XN): xn = xin@WxN.T+bxN; hn = xp@WhN.T+bhN; n = tanh(xn + r*hn);
// out = relu((1-z)*n + z*xp). out may alias R/Z (elementwise), must NOT alias xin/xp.
__global__ __launch_bounds__(THREADS, 2)
void k_gru_fin2(const float* __restrict__ xin, const float* __restrict__ xp,
                const float* __restrict__ wxn, const float* __restrict__ whn,
                const float* __restrict__ bxn, const float* __restrict__ bhn,
                const float* __restrict__ R, const float* __restrict__ Z,
                float* __restrict__ out, int rows){
    const int lane = threadIdx.x & 63;
    const int wid  = blockIdx.x * (blockDim.x >> 6) + (threadIdx.x >> 6);
    const int nw   = gridDim.x * (blockDim.x >> 6);
    float w1[64], w2[64];
    #pragma unroll
    for (int k = 0; k < 64; k += 4){
        float4 a = *(const float4*)(wxn + (size_t)lane * 64 + k);
        w1[k] = a.x; w1[k+1] = a.y; w1[k+2] = a.z; w1[k+3] = a.w;
        float4 b = *(const float4*)(whn + (size_t)lane * 64 + k);
        w2[k] = b.x; w2[k+1] = b.y; w2[k+2] = b.z; w2[k+3] = b.w;
    }
    const float bxl = bxn[lane], bhl = bhn[lane];
    for (int n = wid; n < rows; n += nw){
        const float* a = xin + (size_t)n * 64;
        const float* h = xp  + (size_t)n * 64;
        float xa = bxl, xa1 = 0.f, ha = bhl, ha1 = 0.f;
        #pragma unroll
        for (int k = 0; k < 64; k += 4){
            float4 t = *(const float4*)(a + k);
            xa  = fmaf(t.x, w1[k],   xa);
            xa1 = fmaf(t.y, w1[k+1], xa1);
            xa  = fmaf(t.z, w1[k+2], xa);
            xa1 = fmaf(t.w, w1[k+3], xa1);
        }
        #pragma unroll
        for (int k = 0; k < 64; k += 4){
            float4 t = *(const float4*)(h + k);
            ha  = fmaf(t.x, w2[k],   ha);
            ha1 = fmaf(t.y, w2[k+1], ha1);
            ha  = fmaf(t.z, w2[k+2], ha);
            ha1 = fmaf(t.w, w2[k+3], ha1);
        }
        float xn = xa + xa1, hn = ha + ha1;
        size_t idx = (size_t)n * 64 + lane;
        float r = R[idx], z = Z[idx], hp = h[lane];
        float nn = tanhfast(fmaf(r, hn, xn));
        out[idx] = reluf((1.f - z) * nn + z * hp);
    }
}

// GATEConv per-edge logit
__global__ __launch_bounds__(THREADS, 2)
void k_gate_logit(const float* __restrict__ np1, const float* __restrict__ ea,
                  const float* __restrict__ w1,  // gate_lin1_w [64][80]
                  const float* __restrict__ attl, const float* __restrict__ nat,
                  const int* __restrict__ src, const int* __restrict__ dstv,
                  float* __restrict__ logit, int E){
    __shared__ float wlds[16 * 64];  // [j][k] = w1[k*80 + 64 + j]
    __shared__ float al[64];
    for (int i = threadIdx.x; i < 1024; i += blockDim.x){
        int j = i >> 6, k = i & 63;
        wlds[i] = w1[k * 80 + 64 + j];
    }
    if (threadIdx.x < 64) al[threadIdx.x] = attl[threadIdx.x];
    __syncthreads();
    int e = blockIdx.x * blockDim.x + threadIdx.x;
    if (e >= E) return;
    int s = src[e], d = dstv[e];
    float acc[64];
    const float* nr = np1 + (size_t)s * 64;
    #pragma unroll
    for (int k = 0; k < 64; k += 4){
        float4 t = *(const float4*)(nr + k);
        acc[k] = t.x; acc[k+1] = t.y; acc[k+2] = t.z; acc[k+3] = t.w;
    }
    const float* er = ea + (size_t)e * 16;
    #pragma unroll
    for (int j = 0; j < 16; ++j){
        float v = er[j];
        #pragma unroll
        for (int k = 0; k < 64; k += 4){
            float4 t = *(const float4*)&wlds[j * 64 + k];
            acc[k]   = fmaf(v, t.x, acc[k]);
            acc[k+1] = fmaf(v, t.y, acc[k+1]);
            acc[k+2] = fmaf(v, t.z, acc[k+2]);
            acc[k+3] = fmaf(v, t.w, acc[k+3]);
        }
    }
    float l = 0.f;
    #pragma unroll
    for (int k = 0; k < 64; ++k) l = fmaf(lrelu01(acc[k]), al[k], l);
    logit[e] = lrelu01(l + nat[d]);
}

// GATE aggregate: softmax over stored logits (CSR), h = sum alpha*xg[src] + bias, write elu(h)
__global__ __launch_bounds__(THREADS, 4)
void k_gate_agg(const float* __restrict__ logit, const int* __restrict__ eid,
                const int* __restrict__ rowptr, const int* __restrict__ src,
                const float* __restrict__ xg, const float* __restrict__ bias,
                float* __restrict__ xin, int N){
    const int lane = threadIdx.x & 63;
    const int d = blockIdx.x * (blockDim.x >> 6) + (threadIdx.x >> 6);
    if (d >= N) return;
    int r0 = rowptr[d], r1 = rowptr[d + 1];
    float m = -3.4e38f;
    for (int j = r0 + lane; j < r1; j += 64) m = fmaxf(m, logit[eid[j]]);
    m = wmaxf(m);
    float s = 0.f, hk = 0.f;
    for (int j = r0; j < r1; ++j){
        int e = eid[j];
        float w = __expf(logit[e] - m);
        s += w;
        hk = fmaf(w, xg[(size_t)src[e] * 64 + lane], hk);
    }
    float h = hk / (s + 1e-16f) + bias[lane];
    xin[(size_t)d * 64 + lane] = eluf(h);
}

// GAT aggregate: logits computed inline from asrc[src]+adst[d]
__global__ __launch_bounds__(THREADS, 4)
void k_atom_agg(const float* __restrict__ asrc, const float* __restrict__ adst,
                const int* __restrict__ eid, const int* __restrict__ rowptr,
                const int* __restrict__ src, const float* __restrict__ xl,
                const float* __restrict__ bias, float* __restrict__ xin, int N){
    const int lane = threadIdx.x & 63;
    const int d = blockIdx.x * (blockDim.x >> 6) + (threadIdx.x >> 6);
    if (d >= N) return;
    int r0 = rowptr[d], r1 = rowptr[d + 1];
    const float ad = adst[d];
    float m = -3.4e38f;
    for (int j = r0 + lane; j < r1; j += 64){
        int e = eid[j];
        m = fmaxf(m, lrelu01(asrc[src[e]] + ad));
    }
    m = wmaxf(m);
    float s = 0.f, hk = 0.f;
    for (int j = r0; j < r1; ++j){
        int e = eid[j];
        int sn = src[e];
        float l = lrelu01(asrc[sn] + ad);
        float w = __expf(l - m);
        s += w;
        hk = fmaf(w, xl[(size_t)sn * 64 + lane], hk);
    }
    float h = hk / (s + 1e-16f) + bias[lane];
    xin[(size_t)d * 64 + lane] = eluf(h);
}

// out0[b] = relu(sum over nodes of graph b)
__global__ __launch_bounds__(THREADS, 4)
void k_out0(const float* __restrict__ x, const int* __restrict__ rpB,
            float* __restrict__ outB, int B){
    const int lane = threadIdx.x & 63;
    const int b = blockIdx.x * (blockDim.x >> 6) + (threadIdx.x >> 6);
    if (b >= B) return;
    int r0 = rpB[b], r1 = rpB[b + 1];
    float a = 0.f;
    for (int n = r0; n < r1; ++n) a += x[(size_t)n * 64 + lane];
    outB[(size_t)b * 64 + lane] = reluf(a);
}

// readout attention step: g = (out@W.T)@attdst, softmax over graph nodes, hB = elu(agg + bias)
__global__ __launch_bounds__(THREADS, 4)
void k_mol_attn(const float* __restrict__ outB, const float* __restrict__ W,
                const float* __restrict__ attdst, const float* __restrict__ a_src,
                const float* __restrict__ xs, const int* __restrict__ rpB,
                const float* __restrict__ bias, float* __restrict__ hB, int B){
    const int lane = threadIdx.x & 63;
    const int b = blockIdx.x * (blockDim.x >> 6) + (threadIdx.x >> 6);
    if (b >= B) return;
    float w[64];
    #pragma unroll
    for (int k = 0; k < 64; k += 4){
        float4 t = *(const float4*)(W + (size_t)lane * 64 + k);
        w[k] = t.x; w[k+1] = t.y; w[k+2] = t.z; w[k+3] = t.w;
    }
    const float* orow = outB + (size_t)b * 64;
    float acc = 0.f;
    #pragma unroll
    for (int k = 0; k < 64; ++k) acc = fmaf(orow[k], w[k], acc);
    float g = wsumf(acc * attdst[lane]);
    int r0 = rpB[b], r1 = rpB[b + 1];
    float m = -3.4e38f;
    for (int n = r0 + lane; n < r1; n += 64) m = fmaxf(m, lrelu01(a_src[n] + g));
    m = wmaxf(m);
    float s = 0.f, hk = 0.f;
    for (int n = r0; n < r1; ++n){
        float l = lrelu01(a_src[n] + g);
        float ww = __expf(l - m);
        s += ww;
        hk = fmaf(ww, xs[(size_t)n * 64 + lane], hk);
    }
    hB[(size_t)b * 64 + lane] = eluf(hk / (s + 1e-16f) + bias[lane]);
}

// regression head: LayerNorm -> relu(64x64) -> relu(64x64) -> (Px64)
__global__ void k_head(const float* __restrict__ emb, const float* __restrict__ lng,
                       const float* __restrict__ lnb,
                       const float* __restrict__ w1, const float* __restrict__ b1,
                       const float* __restrict__ w2, const float* __restrict__ b2,
                       const float* __restrict__ w3, const float* __restrict__ b3,
                       float* __restrict__ out, int B, int P){
    __shared__ float w1t[4096], w2t[4096];
    __shared__ float buf0[4][64], buf1[4][64];
    for (int i = threadIdx.x; i < 4096; i += blockDim.x){
        int h = i >> 6, k = i & 63;
        w1t[k * 64 + h] = w1[i];
        w2t[k * 64 + h] = w2[i];
    }
    __syncthreads();
    const int lane = threadIdx.x & 63;
    const int wv = threadIdx.x >> 6;
    int b = blockIdx.x * (blockDim.x >> 6) + wv;
    bool act = b < B;
    float v = act ? emb[(size_t)b * 64 + lane] : 0.f;
    float mean = wsumf(v) * 0.015625f;
    float dv = v - mean;
    float var = wsumf(dv * dv) * 0.015625f;
    float y = dv * rsqrtf(var + 1e-5f) * lng[lane] + lnb[lane];
    buf0[wv][lane] = y;
    __syncthreads();
    float a1 = b1[lane];
    #pragma unroll
    for (int k = 0; k < 64; ++k) a1 = fmaf(buf0[wv][k], w1t[k * 64 + lane], a1);
    float y1 = reluf(a1);
    buf1[wv][lane] = y1;
    __syncthreads();
    float a2 = b2[lane];
    #pragma unroll
    for (int k = 0; k < 64; ++k) a2 = fmaf(buf1[wv][k], w2t[k * 64 + lane], a2);
    float y2 = reluf(a2);
    for (int p = 0; p < P; ++p){
        float s = wsumf(y2 * w3[p * 64 + lane]);
        if (lane == 0 && act) out[(size_t)b * P + p] = s + b3[p];
    }
}

extern "C" void kernel_launch(void* const* d_in, const int* in_sizes, int n_in,
                              void* d_out, int out_size, void* d_ws, size_t ws_size,
                              hipStream_t stream){
    const float* x       = (const float*)d_in[0];
    const float* eattr   = (const float*)d_in[1];
    const float* lin1_w  = (const float*)d_in[2];
    const float* lin1_b  = (const float*)d_in[3];
    const float* g_l1w   = (const float*)d_in[4];
    const float* g_l2w   = (const float*)d_in[5];
    const float* g_attl  = (const float*)d_in[6];
    const float* g_attr  = (const float*)d_in[7];
    const float* g_bias  = (const float*)d_in[8];
    const float* gru0_wx = (const float*)d_in[9];
    const float* gru0_wh = (const float*)d_in[10];
    const float* gru0_bx = (const float*)d_in[11];
    const float* gru0_bh = (const float*)d_in[12];
    const float* a_linw  = (const float*)d_in[13];
    const float* a_asrc  = (const float*)d_in[14];
    const float* a_adst  = (const float*)d_in[15];
    const float* a_bias  = (const float*)d_in[16];
    const float* a_gwx   = (const float*)d_in[17];
    const float* a_gwh   = (const float*)d_in[18];
    const float* a_gbx   = (const float*)d_in[19];
    const float* a_gbh   = (const float*)d_in[20];
    const float* m_linw  = (const float*)d_in[21];
    const float* m_asrcv = (const float*)d_in[22];
    const float* m_adstv = (const float*)d_in[23];
    const float* m_bias  = (const float*)d_in[24];
    const float* m_gwx   = (const float*)d_in[25];
    const float* m_gwh   = (const float*)d_in[26];
    const float* m_gbx   = (const float*)d_in[27];
    const float* m_gbh   = (const float*)d_in[28];
    const float* lin2_w  = (const float*)d_in[29];
    const float* lin2_b  = (const float*)d_in[30];
    const float* ln_g    = (const float*)d_in[31];
    const float* ln_b    = (const float*)d_in[32];
    const float* h1_w    = (const float*)d_in[33];
    const float* h1_b    = (const float*)d_in[34];
    const float* h2_w    = (const float*)d_in[35];
    const float* h2_b    = (const float*)d_in[36];
    const float* h3_w    = (const float*)d_in[37];
    const float* h3_b    = (const float*)d_in[38];
    const int*   ei      = (const int*)d_in[39];
    const int*   batch   = (const int*)d_in[40];
    float* out = (float*)d_out;

    const int N = in_sizes[0] / 64;
    const int E = in_sizes[1] / 16;
    const int P = in_sizes[38];
    const int B = out_size / (P > 0 ? P : 1);
    const int* srcv = ei;
    const int* dstv = ei + E;

    // ---- workspace layout ----
    float* Wb = (float*)d_ws;
    size_t nb = (size_t)N * 64;
    size_t bb = (size_t)B * 64;
    float* P0 = Wb;
    float* P1 = P0 + nb;
    float* P2 = P1 + nb;
    float* P3 = P2 + nb;
    float* P4 = P3 + nb;
    float* logitE = P4 + nb;
    float* scal  = logitE + E;       // 2N floats (nat / asrc,adst / a_src)
    float* outB0 = scal + 2 * (size_t)N;
    float* outB1 = outB0 + bb;
    float* hB    = outB1 + bb;
    float* RB    = hB + bb;
    float* ZB    = RB + bb;
    float* XNB   = ZB + bb;
    int* eid    = (int*)(XNB + bb);
    int* rowptr = eid + E;
    int* cnt    = rowptr + (N + 1);
    int* cnt2   = cnt + N;
    int* rpB    = cnt2 + N;
    size_t need = (size_t)((char*)(rpB + B + 1) - (char*)d_ws);
    if (need > ws_size) return;
    float* embB = XNB;  // reuse (dead by head time)

    dim3 blk(THREADS);
    int gE    = (E + THREADS - 1) / THREADS;
    int gN4   = (N + 3) / 4;
    int gB4   = (B + 3) / 4;
    int gN256 = (N + THREADS - 1) / THREADS;
    int GS_N = 512;    // grid-stride blocks for N-row GEMMs
    int GS_B = 64;     // for B-row GEMMs

    // ---- CSR build ----
    hipMemsetAsync(cnt, 0, sizeof(int) * 2 * (size_t)N, stream);
    k_hist<<<gE, blk, 0, stream>>>(dstv, cnt, E);
    k_scan<<<1, 1024, 0, stream>>>(cnt, rowptr, N);
    k_scatter<<<gE, blk, 0, stream>>>(dstv, rowptr, cnt2, eid, E);
    k_browptr<<<gN256, blk, 0, stream>>>(batch, rpB, N, B);

    // ---- phase 0: x1 = lrelu(x@lin1_w.T + b) -> P0, fused nat = P0@g_attr -> scal ----
    k_gemm64d<1><<<GS_N, blk, 0, stream>>>(x, lin1_w, 64, lin1_b, P0,
                                           g_attr, nullptr, scal, nullptr, N);

    // ---- GATEConv ----
    k_gemm64<0><<<GS_N, blk, 0, stream>>>(P0, g_l1w, 80, nullptr, P1, N);   // np1
    k_gemm64<0><<<GS_N, blk, 0, stream>>>(P0, g_l2w, 64, nullptr, P2, N);   // xg
    k_gate_logit<<<gE, blk, 0, stream>>>(P1, eattr, g_l1w, g_attl, scal, srcv, dstv, logitE, E);
    k_gate_agg<<<gN4, blk, 0, stream>>>(logitE, eid, rowptr, srcv, P2, g_bias, P3, N);
    // GRU0: xin=P3, xprev=P0 -> x=P1
    k_gru_rz<<<dim3(GS_N, 2), blk, 0, stream>>>(P3, P0, gru0_wx, gru0_wh, gru0_bx, gru0_bh, P1, P2, N);
    k_gru_fin2<<<GS_N, blk, 0, stream>>>(P3, P0, gru0_wx + 8192, gru0_wh + 8192,
                                         gru0_bx + 128, gru0_bh + 128, P1, P2, P1, N);

    // ---- atom layer 0: x=P1 -> x=P4 ----
    k_gemm64d<0><<<GS_N, blk, 0, stream>>>(P1, a_linw, 64, nullptr, P0,
                                           a_asrc, a_adst, scal, scal + N, N);
    k_atom_agg<<<gN4, blk, 0, stream>>>(scal, scal + N, eid, rowptr, srcv, P0, a_bias, P3, N);
    k_gru_rz<<<dim3(GS_N, 2), blk, 0, stream>>>(P3, P1, a_gwx, a_gwh, a_gbx, a_gbh, P4, P2, N);
    k_gru_fin2<<<GS_N, blk, 0, stream>>>(P3, P1, a_gwx + 8192, a_gwh + 8192,
                                         a_gbx + 128, a_gbh + 128, P4, P2, P4, N);

    // ---- atom layer 1: x=P4 -> x=P1 ----
    k_gemm64d<0><<<GS_N, blk, 0, stream>>>(P4, a_linw + 4096, 64, nullptr, P0,
                                           a_asrc + 64, a_adst + 64, scal, scal + N, N);
    k_atom_agg<<<gN4, blk, 0, stream>>>(scal, scal + N, eid, rowptr, srcv, P0, a_bias + 64, P3, N);
    k_gru_rz<<<dim3(GS_N, 2), blk, 0, stream>>>(P3, P4, a_gwx + 12288, a_gwh + 12288,
                                                a_gbx + 192, a_gbh + 192, P1, P2, N);
    k_gru_fin2<<<GS_N, blk, 0, stream>>>(P3, P4, a_gwx + 12288 + 8192, a_gwh + 12288 + 8192,
                                         a_gbx + 192 + 128, a_gbh + 192 + 128, P1, P2, P1, N);

    // ---- readout: x=P1 ----
    k_gemm64d<0><<<GS_N, blk, 0, stream>>>(P1, m_linw, 64, nullptr, P0,
                                           m_asrcv, nullptr, scal, nullptr, N);  // xs + a_src
    k_out0<<<gB4, blk, 0, stream>>>(P1, rpB, outB0, B);
    float* cur = outB0;
    float* nxt = outB1;
    for (int t = 0; t < 3; ++t){
        k_mol_attn<<<gB4, blk, 0, stream>>>(cur, m_linw, m_adstv, scal, P0, rpB, m_bias, hB, B);
        k_gru_rz<<<dim3(GS_B, 2), blk, 0, stream>>>(hB, cur, m_gwx, m_gwh, m_gbx, m_gbh, RB, ZB, B);
        k_gru_fin2<<<GS_B, blk, 0, stream>>>(hB, cur, m_gwx + 8192, m_gwh + 8192,
                                             m_gbx + 128, m_gbh + 128, RB, ZB, nxt, B);
        float* tmp = cur; cur = nxt; nxt = tmp;
    }

    // ---- head ----
    k_gemm64<0><<<GS_B, blk, 0, stream>>>(cur, lin2_w, 64, lin2_b, embB, B);
    k_head<<<gB4, blk, 0, stream>>>(embB, ln_g, ln_b, h1_w, h1_b, h2_w, h2_b, h3_w, h3_b, out, B, P);
}

// Round 3
// 1437.840 us; speedup vs baseline: 2.0932x; 1.3248x over previous
//
#include <hip/hip_runtime.h>
#include <cfloat>

#define THREADS 256

__device__ __forceinline__ float lrelu01(float v){ return v > 0.f ? v : 0.01f * v; }
__device__ __forceinline__ float reluf(float v){ return v > 0.f ? v : 0.f; }
__device__ __forceinline__ float sigmf(float v){ return 1.f / (1.f + __expf(-v)); }
__device__ __forceinline__ float tanhfast(float v){
    float t = __expf(-2.f * fabsf(v));
    float r = (1.f - t) / (1.f + t);
    return v < 0.f ? -r : r;
}
__device__ __forceinline__ float eluf(float v){ return v > 0.f ? v : __expf(v) - 1.f; }
__device__ __forceinline__ float wmaxf(float v){
    #pragma unroll
    for (int o = 32; o > 0; o >>= 1) v = fmaxf(v, __shfl_xor(v, o, 64));
    return v;
}
__device__ __forceinline__ float wsumf(float v){
    #pragma unroll
    for (int o = 32; o > 0; o >>= 1) v += __shfl_xor(v, o, 64);
    return v;
}

// ---------------- CSR build ----------------
__global__ void k_hist(const int* __restrict__ dst, int* __restrict__ cnt, int E){
    int e = blockIdx.x * blockDim.x + threadIdx.x;
    if (e < E) atomicAdd(&cnt[dst[e]], 1);
}

__global__ void k_scan(const int* __restrict__ cnt, int* __restrict__ rowptr, int N){
    __shared__ int sums[1024];
    int t = threadIdx.x;
    int CH = (N + 1023) / 1024;
    int s0 = t * CH;
    int s1 = min(N, s0 + CH);
    int tot = 0;
    for (int i = s0; i < s1; ++i) tot += cnt[i];
    sums[t] = tot;
    __syncthreads();
    for (int off = 1; off < 1024; off <<= 1){
        int v = (t >= off) ? sums[t - off] : 0;
        __syncthreads();
        sums[t] += v;
        __syncthreads();
    }
    int run = (t == 0) ? 0 : sums[t - 1];
    for (int i = s0; i < s1; ++i){ rowptr[i] = run; run += cnt[i]; }
    if (t == 1023) rowptr[N] = run;
}

__global__ void k_scatter(const int* __restrict__ dst, const int* __restrict__ rowptr,
                          int* __restrict__ cnt2, int* __restrict__ eid, int E){
    int e = blockIdx.x * blockDim.x + threadIdx.x;
    if (e < E){
        int d = dst[e];
        int p = rowptr[d] + atomicAdd(&cnt2[d], 1);
        eid[p] = e;
    }
}

__global__ void k_browptr(const int* __restrict__ batch, int* __restrict__ rp, int N, int B){
    int n = blockIdx.x * blockDim.x + threadIdx.x;
    if (n >= N) return;
    int b = batch[n];
    int bp = (n == 0) ? -1 : batch[n - 1];
    for (int g = bp + 1; g <= b; ++g) rp[g] = n;
    if (n == N - 1){ for (int g = b + 1; g <= B; ++g) rp[g] = N; }
}

// ---------------- 64-col GEMM: out[n][lane] = act(dot(in[n], W[lane]) + bias) ----------------
// launch_bounds(256,2): REQUIRED — (256,4) leaves the allocator at 64 VGPRs and
// spills w[64] to scratch (R2 profile: 246us, FETCH 375MB, VALUBusy 3%).
template<int ACT>
__global__ __launch_bounds__(THREADS, 2)
void k_gemm64(const float* __restrict__ in, const float* __restrict__ W, int ldw,
              const float* __restrict__ bias, float* __restrict__ out, int rows){
    const int lane = threadIdx.x & 63;
    const int wid  = blockIdx.x * (blockDim.x >> 6) + (threadIdx.x >> 6);
    const int nw   = gridDim.x * (blockDim.x >> 6);
    float w[64];
    #pragma unroll
    for (int k = 0; k < 64; k += 4){
        float4 t = *(const float4*)(W + (size_t)lane * ldw + k);
        w[k] = t.x; w[k+1] = t.y; w[k+2] = t.z; w[k+3] = t.w;
    }
    const float bb = bias ? bias[lane] : 0.f;
    for (int n = wid; n < rows; n += nw){
        const float* __restrict__ xr = in + (size_t)n * 64;
        float a0 = bb, a1 = 0.f;
        #pragma unroll
        for (int k = 0; k < 64; k += 4){
            float4 t = *(const float4*)(xr + k);
            a0 = fmaf(t.x, w[k],   a0);
            a1 = fmaf(t.y, w[k+1], a1);
            a0 = fmaf(t.z, w[k+2], a0);
            a1 = fmaf(t.w, w[k+3], a1);
        }
        float v = a0 + a1;
        if (ACT == 1) v = lrelu01(v);
        else if (ACT == 2) v = reluf(v);
        out[(size_t)n * 64 + lane] = v;
    }
}

// GEMM + fused row-dot epilogue: o0[n] = dot(outrow, v0), o1[n] = dot(outrow, v1)
template<int ACT>
__global__ __launch_bounds__(THREADS, 2)
void k_gemm64d(const float* __restrict__ in, const float* __restrict__ W, int ldw,
               const float* __restrict__ bias, float* __restrict__ out,
               const float* __restrict__ v0, const float* __restrict__ v1,
               float* __restrict__ o0, float* __restrict__ o1, int rows){
    const int lane = threadIdx.x & 63;
    const int wid  = blockIdx.x * (blockDim.x >> 6) + (threadIdx.x >> 6);
    const int nw   = gridDim.x * (blockDim.x >> 6);
    float w[64];
    #pragma unroll
    for (int k = 0; k < 64; k += 4){
        float4 t = *(const float4*)(W + (size_t)lane * ldw + k);
        w[k] = t.x; w[k+1] = t.y; w[k+2] = t.z; w[k+3] = t.w;
    }
    const float bb = bias ? bias[lane] : 0.f;
    const float vl0 = v0 ? v0[lane] : 0.f;
    const float vl1 = v1 ? v1[lane] : 0.f;
    for (int n = wid; n < rows; n += nw){
        const float* __restrict__ xr = in + (size_t)n * 64;
        float a0 = bb, a1 = 0.f;
        #pragma unroll
        for (int k = 0; k < 64; k += 4){
            float4 t = *(const float4*)(xr + k);
            a0 = fmaf(t.x, w[k],   a0);
            a1 = fmaf(t.y, w[k+1], a1);
            a0 = fmaf(t.z, w[k+2], a0);
            a1 = fmaf(t.w, w[k+3], a1);
        }
        float v = a0 + a1;
        if (ACT == 1) v = lrelu01(v);
        else if (ACT == 2) v = reluf(v);
        out[(size_t)n * 64 + lane] = v;
        float s0 = wsumf(v * vl0);
        float s1 = wsumf(v * vl1);
        if (lane == 0){
            if (o0) o0[n] = s0;
            if (o1) o1[n] = s1;
        }
    }
}

// GRU r/z gates: out = sigmoid(xin@WxC.T + bxC + xp@WhC.T + bhC), C = blockIdx.y (0->R,1->Z)
__global__ __launch_bounds__(THREADS, 2)
void k_gru_rz(const float* __restrict__ xin, const float* __restrict__ xp,
              const float* __restrict__ wx, const float* __restrict__ wh,
              const float* __restrict__ bx, const float* __restrict__ bh,
              float* __restrict__ R, float* __restrict__ Z, int rows){
    const int c = blockIdx.y;
    const int lane = threadIdx.x & 63;
    const int wid  = blockIdx.x * (blockDim.x >> 6) + (threadIdx.x >> 6);
    const int nw   = gridDim.x * (blockDim.x >> 6);
    const float* w1p = wx + (size_t)(c * 64 + lane) * 64;
    const float* w2p = wh + (size_t)(c * 64 + lane) * 64;
    float w1[64], w2[64];
    #pragma unroll
    for (int k = 0; k < 64; k += 4){
        float4 a = *(const float4*)(w1p + k);
        w1[k] = a.x; w1[k+1] = a.y; w1[k+2] = a.z; w1[k+3] = a.w;
        float4 b = *(const float4*)(w2p + k);
        w2[k] = b.x; w2[k+1] = b.y; w2[k+2] = b.z; w2[k+3] = b.w;
    }
    const float bb = bx[c * 64 + lane] + bh[c * 64 + lane];
    float* out = c ? Z : R;
    for (int n = wid; n < rows; n += nw){
        const float* a = xin + (size_t)n * 64;
        const float* h = xp  + (size_t)n * 64;
        float acc = bb, acc1 = 0.f;
        #pragma unroll
        for (int k = 0; k < 64; k += 4){
            float4 t = *(const float4*)(a + k);
            acc  = fmaf(t.x, w1[k],   acc);
            acc1 = fmaf(t.y, w1[k+1], acc1);
            acc  = fmaf(t.z, w1[k+2], acc);
            acc1 = fmaf(t.w, w1[k+3], acc1);
        }
        #pragma unroll
        for (int k = 0; k < 64; k += 4){
            float4 t = *(const float4*)(h + k);
            acc  = fmaf(t.x, w2[k],   acc);
            acc1 = fmaf(t.y, w2[k+1], acc1);
            acc  = fmaf(t.z, w2[k+2], acc);
            acc1 = fmaf(t.w, w2[k+3], acc1);
        }
        out[(size_t)n * 64 + lane] = sigmf(acc + acc1);
    }
}

// GRU finish (fused XN): xn = xin@WxN.T+bxN; hn = xp@WhN.T+bhN; n = tanh(xn + r*hn);
// out = relu((1-z)*n + z*xp). out may alias R/Z (elementwise), must NOT alias xin/xp.
__global__ __launch_bounds__(THREADS, 2)
void k_gru_fin2(const float* __restrict__ xin, const float* __restrict__ xp,
                const float* __restrict__ wxn, const float* __restrict__ whn,
                const float* __restrict__ bxn, const float* __restrict__ bhn,
                const float* __restrict__ R, const float* __restrict__ Z,
                float* __restrict__ out, int rows){
    const int lane = threadIdx.x & 63;
    const int wid  = blockIdx.x * (blockDim.x >> 6) + (threadIdx.x >> 6);
    const int nw   = gridDim.x * (blockDim.x >> 6);
    float w1[64], w2[64];
    #pragma unroll
    for (int k = 0; k < 64; k += 4){
        float4 a = *(const float4*)(wxn + (size_t)lane * 64 + k);
        w1[k] = a.x; w1[k+1] = a.y; w1[k+2] = a.z; w1[k+3] = a.w;
        float4 b = *(const float4*)(whn + (size_t)lane * 64 + k);
        w2[k] = b.x; w2[k+1] = b.y; w2[k+2] = b.z; w2[k+3] = b.w;
    }
    const float bxl = bxn[lane], bhl = bhn[lane];
    for (int n = wid; n < rows; n += nw){
        const float* a = xin + (size_t)n * 64;
        const float* h = xp  + (size_t)n * 64;
        float xa = bxl, xa1 = 0.f, ha = bhl, ha1 = 0.f;
        #pragma unroll
        for (int k = 0; k < 64; k += 4){
            float4 t = *(const float4*)(a + k);
            xa  = fmaf(t.x, w1[k],   xa);
            xa1 = fmaf(t.y, w1[k+1], xa1);
            xa  = fmaf(t.z, w1[k+2], xa);
            xa1 = fmaf(t.w, w1[k+3], xa1);
        }
        #pragma unroll
        for (int k = 0; k < 64; k += 4){
            float4 t = *(const float4*)(h + k);
            ha  = fmaf(t.x, w2[k],   ha);
            ha1 = fmaf(t.y, w2[k+1], ha1);
            ha  = fmaf(t.z, w2[k+2], ha);
            ha1 = fmaf(t.w, w2[k+3], ha1);
        }
        float xn = xa + xa1, hn = ha + ha1;
        size_t idx = (size_t)n * 64 + lane;
        float r = R[idx], z = Z[idx], hp = h[lane];
        float nn = tanhfast(fmaf(r, hn, xn));
        out[idx] = reluf((1.f - z) * nn + z * hp);
    }
}

// GATEConv per-edge logit
__global__ __launch_bounds__(THREADS, 2)
void k_gate_logit(const float* __restrict__ np1, const float* __restrict__ ea,
                  const float* __restrict__ w1,  // gate_lin1_w [64][80]
                  const float* __restrict__ attl, const float* __restrict__ nat,
                  const int* __restrict__ src, const int* __restrict__ dstv,
                  float* __restrict__ logit, int E){
    __shared__ float wlds[16 * 64];  // [j][k] = w1[k*80 + 64 + j]
    __shared__ float al[64];
    for (int i = threadIdx.x; i < 1024; i += blockDim.x){
        int j = i >> 6, k = i & 63;
        wlds[i] = w1[k * 80 + 64 + j];
    }
    if (threadIdx.x < 64) al[threadIdx.x] = attl[threadIdx.x];
    __syncthreads();
    int e = blockIdx.x * blockDim.x + threadIdx.x;
    if (e >= E) return;
    int s = src[e], d = dstv[e];
    float acc[64];
    const float* nr = np1 + (size_t)s * 64;
    #pragma unroll
    for (int k = 0; k < 64; k += 4){
        float4 t = *(const float4*)(nr + k);
        acc[k] = t.x; acc[k+1] = t.y; acc[k+2] = t.z; acc[k+3] = t.w;
    }
    const float* er = ea + (size_t)e * 16;
    #pragma unroll
    for (int j = 0; j < 16; ++j){
        float v = er[j];
        #pragma unroll
        for (int k = 0; k < 64; k += 4){
            float4 t = *(const float4*)&wlds[j * 64 + k];
            acc[k]   = fmaf(v, t.x, acc[k]);
            acc[k+1] = fmaf(v, t.y, acc[k+1]);
            acc[k+2] = fmaf(v, t.z, acc[k+2]);
            acc[k+3] = fmaf(v, t.w, acc[k+3]);
        }
    }
    float l = 0.f;
    #pragma unroll
    for (int k = 0; k < 64; ++k) l = fmaf(lrelu01(acc[k]), al[k], l);
    logit[e] = lrelu01(l + nat[d]);
}

// GATE aggregate: softmax over stored logits (CSR), h = sum alpha*xg[src] + bias, write elu(h)
__global__ __launch_bounds__(THREADS, 4)
void k_gate_agg(const float* __restrict__ logit, const int* __restrict__ eid,
                const int* __restrict__ rowptr, const int* __restrict__ src,
                const float* __restrict__ xg, const float* __restrict__ bias,
                float* __restrict__ xin, int N){
    const int lane = threadIdx.x & 63;
    const int d = blockIdx.x * (blockDim.x >> 6) + (threadIdx.x >> 6);
    if (d >= N) return;
    int r0 = rowptr[d], r1 = rowptr[d + 1];
    float m = -3.4e38f;
    for (int j = r0 + lane; j < r1; j += 64) m = fmaxf(m, logit[eid[j]]);
    m = wmaxf(m);
    float s = 0.f, hk = 0.f;
    for (int j = r0; j < r1; ++j){
        int e = eid[j];
        float w = __expf(logit[e] - m);
        s += w;
        hk = fmaf(w, xg[(size_t)src[e] * 64 + lane], hk);
    }
    float h = hk / (s + 1e-16f) + bias[lane];
    xin[(size_t)d * 64 + lane] = eluf(h);
}

// GAT aggregate: logits computed inline from asrc[src]+adst[d]
__global__ __launch_bounds__(THREADS, 4)
void k_atom_agg(const float* __restrict__ asrc, const float* __restrict__ adst,
                const int* __restrict__ eid, const int* __restrict__ rowptr,
                const int* __restrict__ src, const float* __restrict__ xl,
                const float* __restrict__ bias, float* __restrict__ xin, int N){
    const int lane = threadIdx.x & 63;
    const int d = blockIdx.x * (blockDim.x >> 6) + (threadIdx.x >> 6);
    if (d >= N) return;
    int r0 = rowptr[d], r1 = rowptr[d + 1];
    const float ad = adst[d];
    float m = -3.4e38f;
    for (int j = r0 + lane; j < r1; j += 64){
        int e = eid[j];
        m = fmaxf(m, lrelu01(asrc[src[e]] + ad));
    }
    m = wmaxf(m);
    float s = 0.f, hk = 0.f;
    for (int j = r0; j < r1; ++j){
        int e = eid[j];
        int sn = src[e];
        float l = lrelu01(asrc[sn] + ad);
        float w = __expf(l - m);
        s += w;
        hk = fmaf(w, xl[(size_t)sn * 64 + lane], hk);
    }
    float h = hk / (s + 1e-16f) + bias[lane];
    xin[(size_t)d * 64 + lane] = eluf(h);
}

// out0[b] = relu(sum over nodes of graph b)
__global__ __launch_bounds__(THREADS, 4)
void k_out0(const float* __restrict__ x, const int* __restrict__ rpB,
            float* __restrict__ outB, int B){
    const int lane = threadIdx.x & 63;
    const int b = blockIdx.x * (blockDim.x >> 6) + (threadIdx.x >> 6);
    if (b >= B) return;
    int r0 = rpB[b], r1 = rpB[b + 1];
    float a = 0.f;
    for (int n = r0; n < r1; ++n) a += x[(size_t)n * 64 + lane];
    outB[(size_t)b * 64 + lane] = reluf(a);
}

// readout attention step: g = (out@W.T)@attdst, softmax over graph nodes, hB = elu(agg + bias)
__global__ __launch_bounds__(THREADS, 2)
void k_mol_attn(const float* __restrict__ outB, const float* __restrict__ W,
                const float* __restrict__ attdst, const float* __restrict__ a_src,
                const float* __restrict__ xs, const int* __restrict__ rpB,
                const float* __restrict__ bias, float* __restrict__ hB, int B){
    const int lane = threadIdx.x & 63;
    const int b = blockIdx.x * (blockDim.x >> 6) + (threadIdx.x >> 6);
    if (b >= B) return;
    float w[64];
    #pragma unroll
    for (int k = 0; k < 64; k += 4){
        float4 t = *(const float4*)(W + (size_t)lane * 64 + k);
        w[k] = t.x; w[k+1] = t.y; w[k+2] = t.z; w[k+3] = t.w;
    }
    const float* orow = outB + (size_t)b * 64;
    float acc = 0.f;
    #pragma unroll
    for (int k = 0; k < 64; ++k) acc = fmaf(orow[k], w[k], acc);
    float g = wsumf(acc * attdst[lane]);
    int r0 = rpB[b], r1 = rpB[b + 1];
    float m = -3.4e38f;
    for (int n = r0 + lane; n < r1; n += 64) m = fmaxf(m, lrelu01(a_src[n] + g));
    m = wmaxf(m);
    float s = 0.f, hk = 0.f;
    for (int n = r0; n < r1; ++n){
        float l = lrelu01(a_src[n] + g);
        float ww = __expf(l - g * 0.f - m);
        s += ww;
        hk = fmaf(ww, xs[(size_t)n * 64 + lane], hk);
    }
    hB[(size_t)b * 64 + lane] = eluf(hk / (s + 1e-16f) + bias[lane]);
}

// regression head: LayerNorm -> relu(64x64) -> relu(64x64) -> (Px64)
__global__ void k_head(const float* __restrict__ emb, const float* __restrict__ lng,
                       const float* __restrict__ lnb,
                       const float* __restrict__ w1, const float* __restrict__ b1,
                       const float* __restrict__ w2, const float* __restrict__ b2,
                       const float* __restrict__ w3, const float* __restrict__ b3,
                       float* __restrict__ out, int B, int P){
    __shared__ float w1t[4096], w2t[4096];
    __shared__ float buf0[4][64], buf1[4][64];
    for (int i = threadIdx.x; i < 4096; i += blockDim.x){
        int h = i >> 6, k = i & 63;
        w1t[k * 64 + h] = w1[i];
        w2t[k * 64 + h] = w2[i];
    }
    __syncthreads();
    const int lane = threadIdx.x & 63;
    const int wv = threadIdx.x >> 6;
    int b = blockIdx.x * (blockDim.x >> 6) + wv;
    bool act = b < B;
    float v = act ? emb[(size_t)b * 64 + lane] : 0.f;
    float mean = wsumf(v) * 0.015625f;
    float dv = v - mean;
    float var = wsumf(dv * dv) * 0.015625f;
    float y = dv * rsqrtf(var + 1e-5f) * lng[lane] + lnb[lane];
    buf0[wv][lane] = y;
    __syncthreads();
    float a1 = b1[lane];
    #pragma unroll
    for (int k = 0; k < 64; ++k) a1 = fmaf(buf0[wv][k], w1t[k * 64 + lane], a1);
    float y1 = reluf(a1);
    buf1[wv][lane] = y1;
    __syncthreads();
    float a2 = b2[lane];
    #pragma unroll
    for (int k = 0; k < 64; ++k) a2 = fmaf(buf1[wv][k], w2t[k * 64 + lane], a2);
    float y2 = reluf(a2);
    for (int p = 0; p < P; ++p){
        float s = wsumf(y2 * w3[p * 64 + lane]);
        if (lane == 0 && act) out[(size_t)b * P + p] = s + b3[p];
    }
}

extern "C" void kernel_launch(void* const* d_in, const int* in_sizes, int n_in,
                              void* d_out, int out_size, void* d_ws, size_t ws_size,
                              hipStream_t stream){
    const float* x       = (const float*)d_in[0];
    const float* eattr   = (const float*)d_in[1];
    const float* lin1_w  = (const float*)d_in[2];
    const float* lin1_b  = (const float*)d_in[3];
    const float* g_l1w   = (const float*)d_in[4];
    const float* g_l2w   = (const float*)d_in[5];
    const float* g_attl  = (const float*)d_in[6];
    const float* g_attr  = (const float*)d_in[7];
    const float* g_bias  = (const float*)d_in[8];
    const float* gru0_wx = (const float*)d_in[9];
    const float* gru0_wh = (const float*)d_in[10];
    const float* gru0_bx = (const float*)d_in[11];
    const float* gru0_bh = (const float*)d_in[12];
    const float* a_linw  = (const float*)d_in[13];
    const float* a_asrc  = (const float*)d_in[14];
    const float* a_adst  = (const float*)d_in[15];
    const float* a_bias  = (const float*)d_in[16];
    const float* a_gwx   = (const float*)d_in[17];
    const float* a_gwh   = (const float*)d_in[18];
    const float* a_gbx   = (const float*)d_in[19];
    const float* a_gbh   = (const float*)d_in[20];
    const float* m_linw  = (const float*)d_in[21];
    const float* m_asrcv = (const float*)d_in[22];
    const float* m_adstv = (const float*)d_in[23];
    const float* m_bias  = (const float*)d_in[24];
    const float* m_gwx   = (const float*)d_in[25];
    const float* m_gwh   = (const float*)d_in[26];
    const float* m_gbx   = (const float*)d_in[27];
    const float* m_gbh   = (const float*)d_in[28];
    const float* lin2_w  = (const float*)d_in[29];
    const float* lin2_b  = (const float*)d_in[30];
    const float* ln_g    = (const float*)d_in[31];
    const float* ln_b    = (const float*)d_in[32];
    const float* h1_w    = (const float*)d_in[33];
    const float* h1_b    = (const float*)d_in[34];
    const float* h2_w    = (const float*)d_in[35];
    const float* h2_b    = (const float*)d_in[36];
    const float* h3_w    = (const float*)d_in[37];
    const float* h3_b    = (const float*)d_in[38];
    const int*   ei      = (const int*)d_in[39];
    const int*   batch   = (const int*)d_in[40];
    float* out = (float*)d_out;

    const int N = in_sizes[0] / 64;
    const int E = in_sizes[1] / 16;
    const int P = in_sizes[38];
    const int B = out_size / (P > 0 ? P : 1);
    const int* srcv = ei;
    const int* dstv = ei + E;

    // ---- workspace layout ----
    float* Wb = (float*)d_ws;
    size_t nb = (size_t)N * 64;
    size_t bb = (size_t)B * 64;
    float* P0 = Wb;
    float* P1 = P0 + nb;
    float* P2 = P1 + nb;
    float* P3 = P2 + nb;
    float* P4 = P3 + nb;
    float* logitE = P4 + nb;
    float* scal  = logitE + E;       // 2N floats (nat / asrc,adst / a_src)
    float* outB0 = scal + 2 * (size_t)N;
    float* outB1 = outB0 + bb;
    float* hB    = outB1 + bb;
    float* RB    = hB + bb;
    float* ZB    = RB + bb;
    float* XNB   = ZB + bb;
    int* eid    = (int*)(XNB + bb);
    int* rowptr = eid + E;
    int* cnt    = rowptr + (N + 1);
    int* cnt2   = cnt + N;
    int* rpB    = cnt2 + N;
    size_t need = (size_t)((char*)(rpB + B + 1) - (char*)d_ws);
    if (need > ws_size) return;
    float* embB = XNB;  // reuse (dead by head time)

    dim3 blk(THREADS);
    int gE    = (E + THREADS - 1) / THREADS;
    int gN4   = (N + 3) / 4;
    int gB4   = (B + 3) / 4;
    int gN256 = (N + THREADS - 1) / THREADS;
    int GS_N = 512;    // grid-stride blocks for N-row GEMMs
    int GS_B = 64;     // for B-row GEMMs

    // ---- CSR build ----
    hipMemsetAsync(cnt, 0, sizeof(int) * 2 * (size_t)N, stream);
    k_hist<<<gE, blk, 0, stream>>>(dstv, cnt, E);
    k_scan<<<1, 1024, 0, stream>>>(cnt, rowptr, N);
    k_scatter<<<gE, blk, 0, stream>>>(dstv, rowptr, cnt2, eid, E);
    k_browptr<<<gN256, blk, 0, stream>>>(batch, rpB, N, B);

    // ---- phase 0: x1 = lrelu(x@lin1_w.T + b) -> P0, fused nat = P0@g_attr -> scal ----
    k_gemm64d<1><<<GS_N, blk, 0, stream>>>(x, lin1_w, 64, lin1_b, P0,
                                           g_attr, nullptr, scal, nullptr, N);

    // ---- GATEConv ----
    k_gemm64<0><<<GS_N, blk, 0, stream>>>(P0, g_l1w, 80, nullptr, P1, N);   // np1
    k_gemm64<0><<<GS_N, blk, 0, stream>>>(P0, g_l2w, 64, nullptr, P2, N);   // xg
    k_gate_logit<<<gE, blk, 0, stream>>>(P1, eattr, g_l1w, g_attl, scal, srcv, dstv, logitE, E);
    k_gate_agg<<<gN4, blk, 0, stream>>>(logitE, eid, rowptr, srcv, P2, g_bias, P3, N);
    // GRU0: xin=P3, xprev=P0 -> x=P1
    k_gru_rz<<<dim3(GS_N, 2), blk, 0, stream>>>(P3, P0, gru0_wx, gru0_wh, gru0_bx, gru0_bh, P1, P2, N);
    k_gru_fin2<<<GS_N, blk, 0, stream>>>(P3, P0, gru0_wx + 8192, gru0_wh + 8192,
                                         gru0_bx + 128, gru0_bh + 128, P1, P2, P1, N);

    // ---- atom layer 0: x=P1 -> x=P4 ----
    k_gemm64d<0><<<GS_N, blk, 0, stream>>>(P1, a_linw, 64, nullptr, P0,
                                           a_asrc, a_adst, scal, scal + N, N);
    k_atom_agg<<<gN4, blk, 0, stream>>>(scal, scal + N, eid, rowptr, srcv, P0, a_bias, P3, N);
    k_gru_rz<<<dim3(GS_N, 2), blk, 0, stream>>>(P3, P1, a_gwx, a_gwh, a_gbx, a_gbh, P4, P2, N);
    k_gru_fin2<<<GS_N, blk, 0, stream>>>(P3, P1, a_gwx + 8192, a_gwh + 8192,
                                         a_gbx + 128, a_gbh + 128, P4, P2, P4, N);

    // ---- atom layer 1: x=P4 -> x=P1 ----
    k_gemm64d<0><<<GS_N, blk, 0, stream>>>(P4, a_linw + 4096, 64, nullptr, P0,
                                           a_asrc + 64, a_adst + 64, scal, scal + N, N);
    k_atom_agg<<<gN4, blk, 0, stream>>>(scal, scal + N, eid, rowptr, srcv, P0, a_bias + 64, P3, N);
    k_gru_rz<<<dim3(GS_N, 2), blk, 0, stream>>>(P3, P4, a_gwx + 12288, a_gwh + 12288,
                                                a_gbx + 192, a_gbh + 192, P1, P2, N);
    k_gru_fin2<<<GS_N, blk, 0, stream>>>(P3, P4, a_gwx + 12288 + 8192, a_gwh + 12288 + 8192,
                                         a_gbx + 192 + 128, a_gbh + 192 + 128, P1, P2, P1, N);

    // ---- readout: x=P1 ----
    k_gemm64d<0><<<GS_N, blk, 0, stream>>>(P1, m_linw, 64, nullptr, P0,
                                           m_asrcv, nullptr, scal, nullptr, N);  // xs + a_src
    k_out0<<<gB4, blk, 0, stream>>>(P1, rpB, outB0, B);
    float* cur = outB0;
    float* nxt = outB1;
    for (int t = 0; t < 3; ++t){
        k_mol_attn<<<gB4, blk, 0, stream>>>(cur, m_linw, m_adstv, scal, P0, rpB, m_bias, hB, B);
        k_gru_rz<<<dim3(GS_B, 2), blk, 0, stream>>>(hB, cur, m_gwx, m_gwh, m_gbx, m_gbh, RB, ZB, B);
        k_gru_fin2<<<GS_B, blk, 0, stream>>>(hB, cur, m_gwx + 8192, m_gwh + 8192,
                                             m_gbx + 128, m_gbh + 128, RB, ZB, nxt, B);
        float* tmp = cur; cur = nxt; nxt = tmp;
    }

    // ---- head ----
    k_gemm64<0><<<GS_B, blk, 0, stream>>>(cur, lin2_w, 64, lin2_b, embB, B);
    k_head<<<gB4, blk, 0, stream>>>(embB, ln_g, ln_b, h1_w, h1_b, h2_w, h2_b, h3_w, h3_b, out, B, P);
}

// Round 4
// 1383.675 us; speedup vs baseline: 2.1752x; 1.0391x over previous
//
#include <hip/hip_runtime.h>
#include <cfloat>

#define THREADS 256

// Force a value to stay in a VGPR: the compiler cannot rematerialize the load
// past this (asm "may modify" it). Without this, hipcc sinks weight loads into
// the row loop (R3 profile: k_gru_rz VGPR=84 instead of ~190, VALUBusy 10%).
#define PIN(x) asm volatile("" : "+v"(x))

__device__ __forceinline__ float lrelu01(float v){ return v > 0.f ? v : 0.01f * v; }
__device__ __forceinline__ float reluf(float v){ return v > 0.f ? v : 0.f; }
__device__ __forceinline__ float sigmf(float v){ return 1.f / (1.f + __expf(-v)); }
__device__ __forceinline__ float tanhfast(float v){
    float t = __expf(-2.f * fabsf(v));
    float r = (1.f - t) / (1.f + t);
    return v < 0.f ? -r : r;
}
__device__ __forceinline__ float eluf(float v){ return v > 0.f ? v : __expf(v) - 1.f; }
__device__ __forceinline__ float wmaxf(float v){
    #pragma unroll
    for (int o = 32; o > 0; o >>= 1) v = fmaxf(v, __shfl_xor(v, o, 64));
    return v;
}
__device__ __forceinline__ float wsumf(float v){
    #pragma unroll
    for (int o = 32; o > 0; o >>= 1) v += __shfl_xor(v, o, 64);
    return v;
}

// ---------------- CSR build ----------------
__global__ void k_hist(const int* __restrict__ dst, int* __restrict__ cnt, int E){
    int e = blockIdx.x * blockDim.x + threadIdx.x;
    if (e < E) atomicAdd(&cnt[dst[e]], 1);
}

__global__ void k_scan(const int* __restrict__ cnt, int* __restrict__ rowptr, int N){
    __shared__ int sums[1024];
    int t = threadIdx.x;
    int CH = (N + 1023) / 1024;
    int s0 = t * CH;
    int s1 = min(N, s0 + CH);
    int tot = 0;
    for (int i = s0; i < s1; ++i) tot += cnt[i];
    sums[t] = tot;
    __syncthreads();
    for (int off = 1; off < 1024; off <<= 1){
        int v = (t >= off) ? sums[t - off] : 0;
        __syncthreads();
        sums[t] += v;
        __syncthreads();
    }
    int run = (t == 0) ? 0 : sums[t - 1];
    for (int i = s0; i < s1; ++i){ rowptr[i] = run; run += cnt[i]; }
    if (t == 1023) rowptr[N] = run;
}

__global__ void k_scatter(const int* __restrict__ dst, const int* __restrict__ rowptr,
                          int* __restrict__ cnt2, int* __restrict__ eid, int E){
    int e = blockIdx.x * blockDim.x + threadIdx.x;
    if (e < E){
        int d = dst[e];
        int p = rowptr[d] + atomicAdd(&cnt2[d], 1);
        eid[p] = e;
    }
}

__global__ void k_browptr(const int* __restrict__ batch, int* __restrict__ rp, int N, int B){
    int n = blockIdx.x * blockDim.x + threadIdx.x;
    if (n >= N) return;
    int b = batch[n];
    int bp = (n == 0) ? -1 : batch[n - 1];
    for (int g = bp + 1; g <= b; ++g) rp[g] = n;
    if (n == N - 1){ for (int g = b + 1; g <= B; ++g) rp[g] = N; }
}

// ---------------- 64-col GEMM: out[n][lane] = act(dot(in[n], W[lane]) + bias) ----------------
template<int ACT>
__global__ __launch_bounds__(THREADS, 2)
void k_gemm64(const float* __restrict__ in, const float* __restrict__ W, int ldw,
              const float* __restrict__ bias, float* __restrict__ out, int rows){
    const int lane = threadIdx.x & 63;
    const int wid  = blockIdx.x * (blockDim.x >> 6) + (threadIdx.x >> 6);
    const int nw   = gridDim.x * (blockDim.x >> 6);
    float w[64];
    #pragma unroll
    for (int k = 0; k < 64; k += 4){
        float4 t = *(const float4*)(W + (size_t)lane * ldw + k);
        w[k] = t.x; w[k+1] = t.y; w[k+2] = t.z; w[k+3] = t.w;
    }
    #pragma unroll
    for (int k = 0; k < 64; ++k) PIN(w[k]);
    const float bb = bias ? bias[lane] : 0.f;
    for (int n = wid; n < rows; n += nw){
        const float* __restrict__ xr = in + (size_t)n * 64;
        float a0 = bb, a1 = 0.f, a2 = 0.f, a3 = 0.f;
        #pragma unroll
        for (int k = 0; k < 64; k += 4){
            float4 t = *(const float4*)(xr + k);
            a0 = fmaf(t.x, w[k],   a0);
            a1 = fmaf(t.y, w[k+1], a1);
            a2 = fmaf(t.z, w[k+2], a2);
            a3 = fmaf(t.w, w[k+3], a3);
        }
        float v = (a0 + a1) + (a2 + a3);
        if (ACT == 1) v = lrelu01(v);
        else if (ACT == 2) v = reluf(v);
        out[(size_t)n * 64 + lane] = v;
    }
}

// GEMM + fused row-dot epilogue: o0[n] = dot(outrow, v0), o1[n] = dot(outrow, v1)
template<int ACT>
__global__ __launch_bounds__(THREADS, 2)
void k_gemm64d(const float* __restrict__ in, const float* __restrict__ W, int ldw,
               const float* __restrict__ bias, float* __restrict__ out,
               const float* __restrict__ v0, const float* __restrict__ v1,
               float* __restrict__ o0, float* __restrict__ o1, int rows){
    const int lane = threadIdx.x & 63;
    const int wid  = blockIdx.x * (blockDim.x >> 6) + (threadIdx.x >> 6);
    const int nw   = gridDim.x * (blockDim.x >> 6);
    float w[64];
    #pragma unroll
    for (int k = 0; k < 64; k += 4){
        float4 t = *(const float4*)(W + (size_t)lane * ldw + k);
        w[k] = t.x; w[k+1] = t.y; w[k+2] = t.z; w[k+3] = t.w;
    }
    #pragma unroll
    for (int k = 0; k < 64; ++k) PIN(w[k]);
    const float bb = bias ? bias[lane] : 0.f;
    const float vl0 = v0 ? v0[lane] : 0.f;
    const float vl1 = v1 ? v1[lane] : 0.f;
    for (int n = wid; n < rows; n += nw){
        const float* __restrict__ xr = in + (size_t)n * 64;
        float a0 = bb, a1 = 0.f, a2 = 0.f, a3 = 0.f;
        #pragma unroll
        for (int k = 0; k < 64; k += 4){
            float4 t = *(const float4*)(xr + k);
            a0 = fmaf(t.x, w[k],   a0);
            a1 = fmaf(t.y, w[k+1], a1);
            a2 = fmaf(t.z, w[k+2], a2);
            a3 = fmaf(t.w, w[k+3], a3);
        }
        float v = (a0 + a1) + (a2 + a3);
        if (ACT == 1) v = lrelu01(v);
        else if (ACT == 2) v = reluf(v);
        out[(size_t)n * 64 + lane] = v;
        float s0 = wsumf(v * vl0);
        float s1 = wsumf(v * vl1);
        if (lane == 0){
            if (o0) o0[n] = s0;
            if (o1) o1[n] = s1;
        }
    }
}

// GRU r/z gates: out = sigmoid(xin@WxC.T + bxC + xp@WhC.T + bhC), C = blockIdx.y (0->R,1->Z)
__global__ __launch_bounds__(THREADS, 2)
void k_gru_rz(const float* __restrict__ xin, const float* __restrict__ xp,
              const float* __restrict__ wx, const float* __restrict__ wh,
              const float* __restrict__ bx, const float* __restrict__ bh,
              float* __restrict__ R, float* __restrict__ Z, int rows){
    const int c = blockIdx.y;
    const int lane = threadIdx.x & 63;
    const int wid  = blockIdx.x * (blockDim.x >> 6) + (threadIdx.x >> 6);
    const int nw   = gridDim.x * (blockDim.x >> 6);
    const float* w1p = wx + (size_t)(c * 64 + lane) * 64;
    const float* w2p = wh + (size_t)(c * 64 + lane) * 64;
    float w1[64], w2[64];
    #pragma unroll
    for (int k = 0; k < 64; k += 4){
        float4 a = *(const float4*)(w1p + k);
        w1[k] = a.x; w1[k+1] = a.y; w1[k+2] = a.z; w1[k+3] = a.w;
        float4 b = *(const float4*)(w2p + k);
        w2[k] = b.x; w2[k+1] = b.y; w2[k+2] = b.z; w2[k+3] = b.w;
    }
    #pragma unroll
    for (int k = 0; k < 64; ++k){ PIN(w1[k]); PIN(w2[k]); }
    const float bb = bx[c * 64 + lane] + bh[c * 64 + lane];
    float* out = c ? Z : R;
    for (int n = wid; n < rows; n += nw){
        const float* a = xin + (size_t)n * 64;
        const float* h = xp  + (size_t)n * 64;
        float x0 = bb, x1 = 0.f, h0 = 0.f, h1 = 0.f;
        #pragma unroll
        for (int k = 0; k < 64; k += 4){
            float4 t = *(const float4*)(a + k);
            x0 = fmaf(t.x, w1[k],   x0);
            x1 = fmaf(t.y, w1[k+1], x1);
            x0 = fmaf(t.z, w1[k+2], x0);
            x1 = fmaf(t.w, w1[k+3], x1);
        }
        #pragma unroll
        for (int k = 0; k < 64; k += 4){
            float4 t = *(const float4*)(h + k);
            h0 = fmaf(t.x, w2[k],   h0);
            h1 = fmaf(t.y, w2[k+1], h1);
            h0 = fmaf(t.z, w2[k+2], h0);
            h1 = fmaf(t.w, w2[k+3], h1);
        }
        out[(size_t)n * 64 + lane] = sigmf((x0 + x1) + (h0 + h1));
    }
}

// GRU finish (fused XN): xn = xin@WxN.T+bxN; hn = xp@WhN.T+bhN; n = tanh(xn + r*hn);
// out = relu((1-z)*n + z*xp). out may alias R/Z (elementwise), must NOT alias xin/xp.
__global__ __launch_bounds__(THREADS, 2)
void k_gru_fin2(const float* __restrict__ xin, const float* __restrict__ xp,
                const float* __restrict__ wxn, const float* __restrict__ whn,
                const float* __restrict__ bxn, const float* __restrict__ bhn,
                const float* __restrict__ R, const float* __restrict__ Z,
                float* __restrict__ out, int rows){
    const int lane = threadIdx.x & 63;
    const int wid  = blockIdx.x * (blockDim.x >> 6) + (threadIdx.x >> 6);
    const int nw   = gridDim.x * (blockDim.x >> 6);
    float w1[64], w2[64];
    #pragma unroll
    for (int k = 0; k < 64; k += 4){
        float4 a = *(const float4*)(wxn + (size_t)lane * 64 + k);
        w1[k] = a.x; w1[k+1] = a.y; w1[k+2] = a.z; w1[k+3] = a.w;
        float4 b = *(const float4*)(whn + (size_t)lane * 64 + k);
        w2[k] = b.x; w2[k+1] = b.y; w2[k+2] = b.z; w2[k+3] = b.w;
    }
    #pragma unroll
    for (int k = 0; k < 64; ++k){ PIN(w1[k]); PIN(w2[k]); }
    const float bxl = bxn[lane], bhl = bhn[lane];
    for (int n = wid; n < rows; n += nw){
        const float* a = xin + (size_t)n * 64;
        const float* h = xp  + (size_t)n * 64;
        float xa = bxl, xa1 = 0.f, ha = bhl, ha1 = 0.f;
        #pragma unroll
        for (int k = 0; k < 64; k += 4){
            float4 t = *(const float4*)(a + k);
            xa  = fmaf(t.x, w1[k],   xa);
            xa1 = fmaf(t.y, w1[k+1], xa1);
            xa  = fmaf(t.z, w1[k+2], xa);
            xa1 = fmaf(t.w, w1[k+3], xa1);
        }
        #pragma unroll
        for (int k = 0; k < 64; k += 4){
            float4 t = *(const float4*)(h + k);
            ha  = fmaf(t.x, w2[k],   ha);
            ha1 = fmaf(t.y, w2[k+1], ha1);
            ha  = fmaf(t.z, w2[k+2], ha);
            ha1 = fmaf(t.w, w2[k+3], ha1);
        }
        float xn = xa + xa1, hn = ha + ha1;
        size_t idx = (size_t)n * 64 + lane;
        float r = R[idx], z = Z[idx], hp = h[lane];
        float nn = tanhfast(fmaf(r, hn, xn));
        out[idx] = reluf((1.f - z) * nn + z * hp);
    }
}

// GATEConv per-edge logit
__global__ __launch_bounds__(THREADS, 2)
void k_gate_logit(const float* __restrict__ np1, const float* __restrict__ ea,
                  const float* __restrict__ w1,  // gate_lin1_w [64][80]
                  const float* __restrict__ attl, const float* __restrict__ nat,
                  const int* __restrict__ src, const int* __restrict__ dstv,
                  float* __restrict__ logit, int E){
    __shared__ float wlds[16 * 64];  // [j][k] = w1[k*80 + 64 + j]
    __shared__ float al[64];
    for (int i = threadIdx.x; i < 1024; i += blockDim.x){
        int j = i >> 6, k = i & 63;
        wlds[i] = w1[k * 80 + 64 + j];
    }
    if (threadIdx.x < 64) al[threadIdx.x] = attl[threadIdx.x];
    __syncthreads();
    int e = blockIdx.x * blockDim.x + threadIdx.x;
    if (e >= E) return;
    int s = src[e], d = dstv[e];
    float acc[64];
    const float* nr = np1 + (size_t)s * 64;
    #pragma unroll
    for (int k = 0; k < 64; k += 4){
        float4 t = *(const float4*)(nr + k);
        acc[k] = t.x; acc[k+1] = t.y; acc[k+2] = t.z; acc[k+3] = t.w;
    }
    const float* er = ea + (size_t)e * 16;
    #pragma unroll
    for (int j = 0; j < 16; ++j){
        float v = er[j];
        #pragma unroll
        for (int k = 0; k < 64; k += 4){
            float4 t = *(const float4*)&wlds[j * 64 + k];
            acc[k]   = fmaf(v, t.x, acc[k]);
            acc[k+1] = fmaf(v, t.y, acc[k+1]);
            acc[k+2] = fmaf(v, t.z, acc[k+2]);
            acc[k+3] = fmaf(v, t.w, acc[k+3]);
        }
    }
    float l = 0.f;
    #pragma unroll
    for (int k = 0; k < 64; ++k) l = fmaf(lrelu01(acc[k]), al[k], l);
    logit[e] = lrelu01(l + nat[d]);
}

// GATE aggregate: softmax over stored logits (CSR), h = sum alpha*xg[src] + bias, write elu(h)
__global__ __launch_bounds__(THREADS, 4)
void k_gate_agg(const float* __restrict__ logit, const int* __restrict__ eid,
                const int* __restrict__ rowptr, const int* __restrict__ src,
                const float* __restrict__ xg, const float* __restrict__ bias,
                float* __restrict__ xin, int N){
    const int lane = threadIdx.x & 63;
    const int d = blockIdx.x * (blockDim.x >> 6) + (threadIdx.x >> 6);
    if (d >= N) return;
    int r0 = rowptr[d], r1 = rowptr[d + 1];
    float m = -3.4e38f;
    for (int j = r0 + lane; j < r1; j += 64) m = fmaxf(m, logit[eid[j]]);
    m = wmaxf(m);
    float s = 0.f, hk = 0.f;
    for (int j = r0; j < r1; ++j){
        int e = eid[j];
        float w = __expf(logit[e] - m);
        s += w;
        hk = fmaf(w, xg[(size_t)src[e] * 64 + lane], hk);
    }
    float h = hk / (s + 1e-16f) + bias[lane];
    xin[(size_t)d * 64 + lane] = eluf(h);
}

// GAT aggregate: logits computed inline from asrc[src]+adst[d]
__global__ __launch_bounds__(THREADS, 4)
void k_atom_agg(const float* __restrict__ asrc, const float* __restrict__ adst,
                const int* __restrict__ eid, const int* __restrict__ rowptr,
                const int* __restrict__ src, const float* __restrict__ xl,
                const float* __restrict__ bias, float* __restrict__ xin, int N){
    const int lane = threadIdx.x & 63;
    const int d = blockIdx.x * (blockDim.x >> 6) + (threadIdx.x >> 6);
    if (d >= N) return;
    int r0 = rowptr[d], r1 = rowptr[d + 1];
    const float ad = adst[d];
    float m = -3.4e38f;
    for (int j = r0 + lane; j < r1; j += 64){
        int e = eid[j];
        m = fmaxf(m, lrelu01(asrc[src[e]] + ad));
    }
    m = wmaxf(m);
    float s = 0.f, hk = 0.f;
    for (int j = r0; j < r1; ++j){
        int e = eid[j];
        int sn = src[e];
        float l = lrelu01(asrc[sn] + ad);
        float w = __expf(l - m);
        s += w;
        hk = fmaf(w, xl[(size_t)sn * 64 + lane], hk);
    }
    float h = hk / (s + 1e-16f) + bias[lane];
    xin[(size_t)d * 64 + lane] = eluf(h);
}

// out0[b] = relu(sum over nodes of graph b)
__global__ __launch_bounds__(THREADS, 4)
void k_out0(const float* __restrict__ x, const int* __restrict__ rpB,
            float* __restrict__ outB, int B){
    const int lane = threadIdx.x & 63;
    const int b = blockIdx.x * (blockDim.x >> 6) + (threadIdx.x >> 6);
    if (b >= B) return;
    int r0 = rpB[b], r1 = rpB[b + 1];
    float a = 0.f;
    for (int n = r0; n < r1; ++n) a += x[(size_t)n * 64 + lane];
    outB[(size_t)b * 64 + lane] = reluf(a);
}

// readout attention step: g = (out@W.T)@attdst, softmax over graph nodes, hB = elu(agg + bias)
__global__ __launch_bounds__(THREADS, 2)
void k_mol_attn(const float* __restrict__ outB, const float* __restrict__ W,
                const float* __restrict__ attdst, const float* __restrict__ a_src,
                const float* __restrict__ xs, const int* __restrict__ rpB,
                const float* __restrict__ bias, float* __restrict__ hB, int B){
    const int lane = threadIdx.x & 63;
    const int b = blockIdx.x * (blockDim.x >> 6) + (threadIdx.x >> 6);
    if (b >= B) return;
    float w[64];
    #pragma unroll
    for (int k = 0; k < 64; k += 4){
        float4 t = *(const float4*)(W + (size_t)lane * 64 + k);
        w[k] = t.x; w[k+1] = t.y; w[k+2] = t.z; w[k+3] = t.w;
    }
    const float* orow = outB + (size_t)b * 64;
    float acc = 0.f;
    #pragma unroll
    for (int k = 0; k < 64; ++k) acc = fmaf(orow[k], w[k], acc);
    float g = wsumf(acc * attdst[lane]);
    int r0 = rpB[b], r1 = rpB[b + 1];
    float m = -3.4e38f;
    for (int n = r0 + lane; n < r1; n += 64) m = fmaxf(m, lrelu01(a_src[n] + g));
    m = wmaxf(m);
    float s = 0.f, hk = 0.f;
    for (int n = r0; n < r1; ++n){
        float l = lrelu01(a_src[n] + g);
        float ww = __expf(l - m);
        s += ww;
        hk = fmaf(ww, xs[(size_t)n * 64 + lane], hk);
    }
    hB[(size_t)b * 64 + lane] = eluf(hk / (s + 1e-16f) + bias[lane]);
}

// regression head: LayerNorm -> relu(64x64) -> relu(64x64) -> (Px64)
__global__ void k_head(const float* __restrict__ emb, const float* __restrict__ lng,
                       const float* __restrict__ lnb,
                       const float* __restrict__ w1, const float* __restrict__ b1,
                       const float* __restrict__ w2, const float* __restrict__ b2,
                       const float* __restrict__ w3, const float* __restrict__ b3,
                       float* __restrict__ out, int B, int P){
    __shared__ float w1t[4096], w2t[4096];
    __shared__ float buf0[4][64], buf1[4][64];
    for (int i = threadIdx.x; i < 4096; i += blockDim.x){
        int h = i >> 6, k = i & 63;
        w1t[k * 64 + h] = w1[i];
        w2t[k * 64 + h] = w2[i];
    }
    __syncthreads();
    const int lane = threadIdx.x & 63;
    const int wv = threadIdx.x >> 6;
    int b = blockIdx.x * (blockDim.x >> 6) + wv;
    bool act = b < B;
    float v = act ? emb[(size_t)b * 64 + lane] : 0.f;
    float mean = wsumf(v) * 0.015625f;
    float dv = v - mean;
    float var = wsumf(dv * dv) * 0.015625f;
    float y = dv * rsqrtf(var + 1e-5f) * lng[lane] + lnb[lane];
    buf0[wv][lane] = y;
    __syncthreads();
    float a1 = b1[lane];
    #pragma unroll
    for (int k = 0; k < 64; ++k) a1 = fmaf(buf0[wv][k], w1t[k * 64 + lane], a1);
    float y1 = reluf(a1);
    buf1[wv][lane] = y1;
    __syncthreads();
    float a2 = b2[lane];
    #pragma unroll
    for (int k = 0; k < 64; ++k) a2 = fmaf(buf1[wv][k], w2t[k * 64 + lane], a2);
    float y2 = reluf(a2);
    for (int p = 0; p < P; ++p){
        float s = wsumf(y2 * w3[p * 64 + lane]);
        if (lane == 0 && act) out[(size_t)b * P + p] = s + b3[p];
    }
}

extern "C" void kernel_launch(void* const* d_in, const int* in_sizes, int n_in,
                              void* d_out, int out_size, void* d_ws, size_t ws_size,
                              hipStream_t stream){
    const float* x       = (const float*)d_in[0];
    const float* eattr   = (const float*)d_in[1];
    const float* lin1_w  = (const float*)d_in[2];
    const float* lin1_b  = (const float*)d_in[3];
    const float* g_l1w   = (const float*)d_in[4];
    const float* g_l2w   = (const float*)d_in[5];
    const float* g_attl  = (const float*)d_in[6];
    const float* g_attr  = (const float*)d_in[7];
    const float* g_bias  = (const float*)d_in[8];
    const float* gru0_wx = (const float*)d_in[9];
    const float* gru0_wh = (const float*)d_in[10];
    const float* gru0_bx = (const float*)d_in[11];
    const float* gru0_bh = (const float*)d_in[12];
    const float* a_linw  = (const float*)d_in[13];
    const float* a_asrc  = (const float*)d_in[14];
    const float* a_adst  = (const float*)d_in[15];
    const float* a_bias  = (const float*)d_in[16];
    const float* a_gwx   = (const float*)d_in[17];
    const float* a_gwh   = (const float*)d_in[18];
    const float* a_gbx   = (const float*)d_in[19];
    const float* a_gbh   = (const float*)d_in[20];
    const float* m_linw  = (const float*)d_in[21];
    const float* m_asrcv = (const float*)d_in[22];
    const float* m_adstv = (const float*)d_in[23];
    const float* m_bias  = (const float*)d_in[24];
    const float* m_gwx   = (const float*)d_in[25];
    const float* m_gwh   = (const float*)d_in[26];
    const float* m_gbx   = (const float*)d_in[27];
    const float* m_gbh   = (const float*)d_in[28];
    const float* lin2_w  = (const float*)d_in[29];
    const float* lin2_b  = (const float*)d_in[30];
    const float* ln_g    = (const float*)d_in[31];
    const float* ln_b    = (const float*)d_in[32];
    const float* h1_w    = (const float*)d_in[33];
    const float* h1_b    = (const float*)d_in[34];
    const float* h2_w    = (const float*)d_in[35];
    const float* h2_b    = (const float*)d_in[36];
    const float* h3_w    = (const float*)d_in[37];
    const float* h3_b    = (const float*)d_in[38];
    const int*   ei      = (const int*)d_in[39];
    const int*   batch   = (const int*)d_in[40];
    float* out = (float*)d_out;

    const int N = in_sizes[0] / 64;
    const int E = in_sizes[1] / 16;
    const int P = in_sizes[38];
    const int B = out_size / (P > 0 ? P : 1);
    const int* srcv = ei;
    const int* dstv = ei + E;

    // ---- workspace layout ----
    float* Wb = (float*)d_ws;
    size_t nb = (size_t)N * 64;
    size_t bb = (size_t)B * 64;
    float* P0 = Wb;
    float* P1 = P0 + nb;
    float* P2 = P1 + nb;
    float* P3 = P2 + nb;
    float* P4 = P3 + nb;
    float* logitE = P4 + nb;
    float* scal  = logitE + E;       // 2N floats (nat / asrc,adst / a_src)
    float* outB0 = scal + 2 * (size_t)N;
    float* outB1 = outB0 + bb;
    float* hB    = outB1 + bb;
    float* RB    = hB + bb;
    float* ZB    = RB + bb;
    float* XNB   = ZB + bb;
    int* eid    = (int*)(XNB + bb);
    int* rowptr = eid + E;
    int* cnt    = rowptr + (N + 1);
    int* cnt2   = cnt + N;
    int* rpB    = cnt2 + N;
    size_t need = (size_t)((char*)(rpB + B + 1) - (char*)d_ws);
    if (need > ws_size) return;
    float* embB = XNB;  // reuse (dead by head time)

    dim3 blk(THREADS);
    int gE    = (E + THREADS - 1) / THREADS;
    int gN4   = (N + 3) / 4;
    int gB4   = (B + 3) / 4;
    int gN256 = (N + THREADS - 1) / THREADS;
    int GS_N = 512;    // grid-stride blocks for N-row GEMMs
    int GS_B = 64;     // for B-row GEMMs

    // ---- CSR build ----
    hipMemsetAsync(cnt, 0, sizeof(int) * 2 * (size_t)N, stream);
    k_hist<<<gE, blk, 0, stream>>>(dstv, cnt, E);
    k_scan<<<1, 1024, 0, stream>>>(cnt, rowptr, N);
    k_scatter<<<gE, blk, 0, stream>>>(dstv, rowptr, cnt2, eid, E);
    k_browptr<<<gN256, blk, 0, stream>>>(batch, rpB, N, B);

    // ---- phase 0: x1 = lrelu(x@lin1_w.T + b) -> P0, fused nat = P0@g_attr -> scal ----
    k_gemm64d<1><<<GS_N, blk, 0, stream>>>(x, lin1_w, 64, lin1_b, P0,
                                           g_attr, nullptr, scal, nullptr, N);

    // ---- GATEConv ----
    k_gemm64<0><<<GS_N, blk, 0, stream>>>(P0, g_l1w, 80, nullptr, P1, N);   // np1
    k_gemm64<0><<<GS_N, blk, 0, stream>>>(P0, g_l2w, 64, nullptr, P2, N);   // xg
    k_gate_logit<<<gE, blk, 0, stream>>>(P1, eattr, g_l1w, g_attl, scal, srcv, dstv, logitE, E);
    k_gate_agg<<<gN4, blk, 0, stream>>>(logitE, eid, rowptr, srcv, P2, g_bias, P3, N);
    // GRU0: xin=P3, xprev=P0 -> x=P1
    k_gru_rz<<<dim3(GS_N, 2), blk, 0, stream>>>(P3, P0, gru0_wx, gru0_wh, gru0_bx, gru0_bh, P1, P2, N);
    k_gru_fin2<<<GS_N, blk, 0, stream>>>(P3, P0, gru0_wx + 8192, gru0_wh + 8192,
                                         gru0_bx + 128, gru0_bh + 128, P1, P2, P1, N);

    // ---- atom layer 0: x=P1 -> x=P4 ----
    k_gemm64d<0><<<GS_N, blk, 0, stream>>>(P1, a_linw, 64, nullptr, P0,
                                           a_asrc, a_adst, scal, scal + N, N);
    k_atom_agg<<<gN4, blk, 0, stream>>>(scal, scal + N, eid, rowptr, srcv, P0, a_bias, P3, N);
    k_gru_rz<<<dim3(GS_N, 2), blk, 0, stream>>>(P3, P1, a_gwx, a_gwh, a_gbx, a_gbh, P4, P2, N);
    k_gru_fin2<<<GS_N, blk, 0, stream>>>(P3, P1, a_gwx + 8192, a_gwh + 8192,
                                         a_gbx + 128, a_gbh + 128, P4, P2, P4, N);

    // ---- atom layer 1: x=P4 -> x=P1 ----
    k_gemm64d<0><<<GS_N, blk, 0, stream>>>(P4, a_linw + 4096, 64, nullptr, P0,
                                           a_asrc + 64, a_adst + 64, scal, scal + N, N);
    k_atom_agg<<<gN4, blk, 0, stream>>>(scal, scal + N, eid, rowptr, srcv, P0, a_bias + 64, P3, N);
    k_gru_rz<<<dim3(GS_N, 2), blk, 0, stream>>>(P3, P4, a_gwx + 12288, a_gwh + 12288,
                                                a_gbx + 192, a_gbh + 192, P1, P2, N);
    k_gru_fin2<<<GS_N, blk, 0, stream>>>(P3, P4, a_gwx + 12288 + 8192, a_gwh + 12288 + 8192,
                                         a_gbx + 192 + 128, a_gbh + 192 + 128, P1, P2, P1, N);

    // ---- readout: x=P1 ----
    k_gemm64d<0><<<GS_N, blk, 0, stream>>>(P1, m_linw, 64, nullptr, P0,
                                           m_asrcv, nullptr, scal, nullptr, N);  // xs + a_src
    k_out0<<<gB4, blk, 0, stream>>>(P1, rpB, outB0, B);
    float* cur = outB0;
    float* nxt = outB1;
    for (int t = 0; t < 3; ++t){
        k_mol_attn<<<gB4, blk, 0, stream>>>(cur, m_linw, m_adstv, scal, P0, rpB, m_bias, hB, B);
        k_gru_rz<<<dim3(GS_B, 2), blk, 0, stream>>>(hB, cur, m_gwx, m_gwh, m_gbx, m_gbh, RB, ZB, B);
        k_gru_fin2<<<GS_B, blk, 0, stream>>>(hB, cur, m_gwx + 8192, m_gwh + 8192,
                                             m_gbx + 128, m_gbh + 128, RB, ZB, nxt, B);
        float* tmp = cur; cur = nxt; nxt = tmp;
    }

    // ---- head ----
    k_gemm64<0><<<GS_B, blk, 0, stream>>>(cur, lin2_w, 64, lin2_b, embB, B);
    k_head<<<gB4, blk, 0, stream>>>(embB, ln_g, ln_b, h1_w, h1_b, h2_w, h2_b, h3_w, h3_b, out, B, P);
}